// Round 1
// baseline (3062.441 us; speedup 1.0000x reference)
//
#include <hip/hip_runtime.h>
#include <math.h>

// ---------------------------------------------------------------------------
// BurstDeblurNet — frame-0-only fp32 implementation.
// Only burst[:,0] reaches the output and all ops are batch-independent,
// so we process a single 3x256x256 frame. ~59 GFLOP total.
// ---------------------------------------------------------------------------

static __device__ __forceinline__ float gelu_f(float x) {
    float x3 = x * x * x;
    return 0.5f * x * (1.f + tanhf(0.7978845608028654f * (x + 0.044715f * x3)));
}

// ---- generic 3x3 pad-1 conv, optional 2-tensor (concat) input, act, NHWC out
template <int OCB>
__global__ __launch_bounds__(256) void conv3x3_kernel(
    const float* __restrict__ in1, int C1, const float* __restrict__ in2, int C2,
    const float* __restrict__ w, const float* __restrict__ bias,
    float* __restrict__ out, int H, int W, int OC, int act, int nhwc_out)
{
    int tx = threadIdx.x, ty = threadIdx.y;
    int x = blockIdx.x * 16 + tx, y = blockIdx.y * 16 + ty;
    int oc0 = blockIdx.z * OCB;
    int C = C1 + C2;
    float acc[OCB];
#pragma unroll
    for (int o = 0; o < OCB; ++o) acc[o] = 0.f;
    for (int ic = 0; ic < C; ++ic) {
        const float* src = (ic < C1) ? (in1 + (size_t)ic * H * W)
                                     : (in2 + (size_t)(ic - C1) * H * W);
        float v[9];
#pragma unroll
        for (int ky = 0; ky < 3; ++ky) {
            int iy = y + ky - 1;
            bool okY = (iy >= 0) && (iy < H);
#pragma unroll
            for (int kx = 0; kx < 3; ++kx) {
                int ix = x + kx - 1;
                bool ok = okY && (ix >= 0) && (ix < W);
                v[ky * 3 + kx] = ok ? src[(size_t)iy * W + ix] : 0.f;
            }
        }
        const float* wp = w + ((size_t)oc0 * C + ic) * 9;
#pragma unroll
        for (int o = 0; o < OCB; ++o) {
            const float* wo = wp + (size_t)o * C * 9;
            acc[o] += v[0]*wo[0] + v[1]*wo[1] + v[2]*wo[2]
                    + v[3]*wo[3] + v[4]*wo[4] + v[5]*wo[5]
                    + v[6]*wo[6] + v[7]*wo[7] + v[8]*wo[8];
        }
    }
#pragma unroll
    for (int o = 0; o < OCB; ++o) {
        int oc = oc0 + o;
        float r = acc[o] + bias[oc];
        if (act == 1) r = fmaxf(r, 0.f);
        else if (act == 2) r = 1.f / (1.f + expf(-r));
        if (nhwc_out) out[(size_t)(y * W + x) * OC + oc] = r;
        else          out[(size_t)oc * H * W + (size_t)y * W + x] = r;
    }
}

// ---- 2x2 max pool, stride 2
__global__ __launch_bounds__(256) void maxpool_kernel(
    const float* __restrict__ in, float* __restrict__ out, int C, int IH, int IW)
{
    int OH = IH >> 1, OW = IW >> 1;
    int idx = blockIdx.x * 256 + threadIdx.x;
    int total = C * OH * OW;
    if (idx >= total) return;
    int x = idx % OW; int t = idx / OW; int y = t % OH; int c = t / OH;
    const float* p = in + (size_t)c * IH * IW + (size_t)(2 * y) * IW + 2 * x;
    out[idx] = fmaxf(fmaxf(p[0], p[1]), fmaxf(p[IW], p[IW + 1]));
}

// ---- ConvTranspose2d k=4 s=2 p=1. Parity-split blocks -> uniform kernel taps.
// w layout (torch): [IC][OC][4][4].  out[oy]=sum in[iy]*w[ky], oy=2*iy+ky-1.
template <int OCB>
__global__ __launch_bounds__(256) void convt4x4_kernel(
    const float* __restrict__ in, int IC, const float* __restrict__ w,
    const float* __restrict__ bias, float* __restrict__ out,
    int IH, int IW, int OC, int in_nhwc)
{
    int OH = IH * 2, OW = IW * 2;
    int pz = blockIdx.z;
    int py = pz & 1, px = (pz >> 1) & 1;
    int oc0 = (pz >> 2) * OCB;
    int oy = blockIdx.y * 32 + threadIdx.y * 2 + py;
    int ox = blockIdx.x * 32 + threadIdx.x * 2 + px;
    int ky0 = (oy + 1) & 1, kx0 = (ox + 1) & 1;  // uniform per block
    int iy[2], ix[2]; bool vy[2], vx[2];
#pragma unroll
    for (int t = 0; t < 2; ++t) {
        int ny = oy + 1 - (ky0 + 2 * t);
        iy[t] = ny >> 1; vy[t] = (ny >= 0) && (iy[t] < IH);
        int nx = ox + 1 - (kx0 + 2 * t);
        ix[t] = nx >> 1; vx[t] = (nx >= 0) && (ix[t] < IW);
    }
    float acc[OCB];
#pragma unroll
    for (int o = 0; o < OCB; ++o) acc[o] = 0.f;
    for (int ic = 0; ic < IC; ++ic) {
        float vin[4];
#pragma unroll
        for (int a = 0; a < 2; ++a)
#pragma unroll
            for (int b = 0; b < 2; ++b) {
                bool ok = vy[a] && vx[b];
                size_t off = in_nhwc ? ((size_t)(iy[a] * IW + ix[b]) * IC + ic)
                                     : ((size_t)ic * IH * IW + (size_t)iy[a] * IW + ix[b]);
                vin[a * 2 + b] = ok ? in[off] : 0.f;
            }
        const float* wp = w + ((size_t)ic * OC + oc0) * 16;
#pragma unroll
        for (int o = 0; o < OCB; ++o) {
            const float* wo = wp + o * 16;
            acc[o] += vin[0] * wo[ky0 * 4 + kx0]
                    + vin[1] * wo[ky0 * 4 + kx0 + 2]
                    + vin[2] * wo[(ky0 + 2) * 4 + kx0]
                    + vin[3] * wo[(ky0 + 2) * 4 + kx0 + 2];
        }
    }
#pragma unroll
    for (int o = 0; o < OCB; ++o) {
        int oc = oc0 + o;
        out[(size_t)oc * OH * OW + (size_t)oy * OW + ox] = acc[o] + bias[oc];
    }
}

// ---- LayerNorm over 256 dims, one wave per token
__global__ __launch_bounds__(256) void ln_kernel(
    const float* __restrict__ x, const float* __restrict__ g,
    const float* __restrict__ b, float* __restrict__ y)
{
    int wave = threadIdx.x >> 6, lane = threadIdx.x & 63;
    int n = blockIdx.x * 4 + wave;
    const float* xr = x + (size_t)n * 256;
    float4 v = *(const float4*)(xr + lane * 4);
    float s = v.x + v.y + v.z + v.w;
#pragma unroll
    for (int m = 1; m < 64; m <<= 1) s += __shfl_xor(s, m);
    float mean = s * (1.f / 256.f);
    float cx = v.x - mean, cy = v.y - mean, cz = v.z - mean, cw = v.w - mean;
    float q = cx * cx + cy * cy + cz * cz + cw * cw;
#pragma unroll
    for (int m = 1; m < 64; m <<= 1) q += __shfl_xor(q, m);
    float rstd = rsqrtf(q * (1.f / 256.f) + 1e-5f);
    float4 gv = *(const float4*)(g + lane * 4);
    float4 bv = *(const float4*)(b + lane * 4);
    float4 o;
    o.x = cx * rstd * gv.x + bv.x;
    o.y = cy * rstd * gv.y + bv.y;
    o.z = cz * rstd * gv.z + bv.z;
    o.w = cw * rstd * gv.w + bv.w;
    *(float4*)(y + (size_t)n * 256 + lane * 4) = o;
}

// ---- fp32 GEMM: C[M,N] = act(A[M,K] @ W[K,N] + bias) (+C if resid)
__global__ __launch_bounds__(256) void gemm_kernel(
    const float* __restrict__ A, const float* __restrict__ W,
    const float* __restrict__ bias, float* __restrict__ C,
    int M, int N, int K, int act, int resid)
{
    __shared__ float As[64][17];
    __shared__ float Ws[16][64];
    int tid = threadIdx.x;
    int tx = tid & 15, ty = tid >> 4;
    int m0 = blockIdx.y * 64, n0 = blockIdx.x * 64;
    int la_m = tid >> 2, la_k = (tid & 3) * 4;
    int lw_k = tid >> 4, lw_n = (tid & 15) * 4;
    float acc[4][4];
#pragma unroll
    for (int i = 0; i < 4; ++i)
#pragma unroll
        for (int j = 0; j < 4; ++j) acc[i][j] = 0.f;
    for (int k0 = 0; k0 < K; k0 += 16) {
        float4 av = *(const float4*)(A + (size_t)(m0 + la_m) * K + k0 + la_k);
        float4 wv = *(const float4*)(W + (size_t)(k0 + lw_k) * N + n0 + lw_n);
        As[la_m][la_k + 0] = av.x; As[la_m][la_k + 1] = av.y;
        As[la_m][la_k + 2] = av.z; As[la_m][la_k + 3] = av.w;
        *(float4*)(&Ws[lw_k][lw_n]) = wv;
        __syncthreads();
#pragma unroll
        for (int kk = 0; kk < 16; ++kk) {
            float a0 = As[ty * 4 + 0][kk], a1 = As[ty * 4 + 1][kk];
            float a2 = As[ty * 4 + 2][kk], a3 = As[ty * 4 + 3][kk];
            float4 wq = *(const float4*)(&Ws[kk][tx * 4]);
            acc[0][0] += a0 * wq.x; acc[0][1] += a0 * wq.y; acc[0][2] += a0 * wq.z; acc[0][3] += a0 * wq.w;
            acc[1][0] += a1 * wq.x; acc[1][1] += a1 * wq.y; acc[1][2] += a1 * wq.z; acc[1][3] += a1 * wq.w;
            acc[2][0] += a2 * wq.x; acc[2][1] += a2 * wq.y; acc[2][2] += a2 * wq.z; acc[2][3] += a2 * wq.w;
            acc[3][0] += a3 * wq.x; acc[3][1] += a3 * wq.y; acc[3][2] += a3 * wq.z; acc[3][3] += a3 * wq.w;
        }
        __syncthreads();
    }
#pragma unroll
    for (int i = 0; i < 4; ++i) {
        int cm = m0 + ty * 4 + i;
#pragma unroll
        for (int j = 0; j < 4; ++j) {
            int cn = n0 + tx * 4 + j;
            float v = acc[i][j] + bias[cn];
            if (act == 1) v = gelu_f(v);
            float* cp = C + (size_t)cm * N + cn;
            if (resid) v += *cp;
            *cp = v;
        }
    }
}

// ---- per-(head, token) 1/(||qk||+1e-6)
__global__ __launch_bounds__(256) void knorm_kernel(
    const float* __restrict__ qk, float* __restrict__ knrm)
{
    int t = blockIdx.x * 256 + threadIdx.x;   // [0, 16384)
    int h = t >> 12, n = t & 4095;
    const float* q = qk + (size_t)n * 256 + h * 64;
    float s = 0.f;
#pragma unroll
    for (int d = 0; d < 64; d += 4) {
        float4 v = *(const float4*)(q + d);
        s += v.x * v.x + v.y * v.y + v.z * v.z + v.w * v.w;
    }
    knrm[t] = 1.f / (sqrtf(s) + 1e-6f);
}

// ---- LSH bucket: argmax over [rot, -rot] projections (first-max semantics)
__global__ __launch_bounds__(256) void bucket_kernel(
    const float* __restrict__ qk, const float* __restrict__ rot,
    int* __restrict__ buckets)
{
    int t = blockIdx.x * 256 + threadIdx.x;
    int h = t >> 12, n = t & 4095;
    const float* q = qk + (size_t)n * 256 + h * 64;
    const float* R = rot + (size_t)h * 2048;   // [64][32]
    float acc[32];
#pragma unroll
    for (int r = 0; r < 32; ++r) acc[r] = 0.f;
    for (int d = 0; d < 64; ++d) {
        float qd = q[d];
        const float* Rd = R + d * 32;
#pragma unroll
        for (int r = 0; r < 32; ++r) acc[r] += qd * Rd[r];
    }
    float bvv = acc[0]; int best = 0;
#pragma unroll
    for (int j = 1; j < 64; ++j) {
        float val = (j < 32) ? acc[j] : -acc[j - 32];
        if (val > bvv) { bvv = val; best = j; }
    }
    buckets[t] = best;
}

// ---- stable counting sort by bucket (== argsort(bucket*N + idx)), per head.
// 4096-bit membership mask per bucket built with wave ballots.
__global__ __launch_bounds__(256) void lsh_sort_kernel(
    const int* __restrict__ buckets, int* __restrict__ perm)
{
    int h = blockIdx.x;
    const int* bk = buckets + h * 4096;
    __shared__ unsigned long long mask[64][64];  // [bucket][word]
    __shared__ int counts[64];
    __shared__ int offsets[64];
    __shared__ int wpre[64][64];
    int tid = threadIdx.x, wave = tid >> 6, lane = tid & 63;
    for (int w = wave * 16; w < wave * 16 + 16; ++w) {
        int bl = bk[w * 64 + lane];
        for (int b = 0; b < 64; ++b) {
            unsigned long long m = __ballot(bl == b);
            if (lane == b) mask[b][w] = m;
        }
    }
    __syncthreads();
    if (tid < 64) {
        int c = 0;
        for (int w = 0; w < 64; ++w) c += __popcll(mask[tid][w]);
        counts[tid] = c;
    }
    __syncthreads();
    if (tid == 0) {
        int a = 0;
        for (int b = 0; b < 64; ++b) { offsets[b] = a; a += counts[b]; }
    }
    __syncthreads();
    for (int b = wave * 16; b < wave * 16 + 16; ++b) {
        int c = __popcll(mask[b][lane]);   // lane = word index
        int incl = c;
#pragma unroll
        for (int off = 1; off < 64; off <<= 1) {
            int nb = __shfl_up(incl, off);
            if (lane >= off) incl += nb;
        }
        wpre[b][lane] = incl - c + offsets[b];
    }
    __syncthreads();
    for (int i = tid; i < 4096; i += 256) {
        int b = bk[i]; int w = i >> 6; int l = i & 63;
        unsigned long long below = mask[b][w] & ((1ull << l) - 1ull);
        int pos = wpre[b][w] + __popcll(below);
        perm[h * 4096 + pos] = i;
    }
}

// ---- chunked LSH attention: 64 queries x 128 keys (chunk + previous chunk).
// Writes o[token][head*64+d] directly through perm (no inverse perm needed).
__global__ __launch_bounds__(256) void attn_kernel(
    const float* __restrict__ qk, const float* __restrict__ vv,
    const float* __restrict__ knrm, const int* __restrict__ perm,
    float* __restrict__ o)
{
    __shared__ float ks[128 * 64];     // keys, then reused for values
    __shared__ float dotsT[128 * 64];  // [j][r] transposed scores
    int c = blockIdx.x, h = blockIdx.y;
    int tid = threadIdx.x;
    const int* pm = perm + h * 4096;
    int cm = (c + 63) & 63;
    // stage normalized keys
    {
        int jr = tid >> 1, hf = tid & 1;
        int sk = (jr < 64) ? (c * 64 + jr) : (cm * 64 + (jr - 64));
        int nk = pm[sk];
        float sc = knrm[h * 4096 + nk];
        const float* src = qk + (size_t)nk * 256 + h * 64 + hf * 32;
        float* dst = ks + jr * 64 + hf * 32;
#pragma unroll
        for (int d = 0; d < 32; d += 4) {
            float4 v = *(const float4*)(src + d);
            v.x *= sc; v.y *= sc; v.z *= sc; v.w *= sc;
            *(float4*)(dst + d) = v;
        }
    }
    __syncthreads();
    int r = tid & 63, jg = tid >> 6;
    int nq = pm[c * 64 + r];
    {
        float qreg[64];
        const float* src = qk + (size_t)nq * 256 + h * 64;
#pragma unroll
        for (int d = 0; d < 64; d += 4) {
            float4 v = *(const float4*)(src + d);
            qreg[d] = v.x; qreg[d + 1] = v.y; qreg[d + 2] = v.z; qreg[d + 3] = v.w;
        }
        for (int j = jg * 32; j < jg * 32 + 32; ++j) {
            const float* kr = ks + j * 64;   // j uniform per wave -> broadcast
            float dot = 0.f;
#pragma unroll
            for (int d = 0; d < 64; ++d) dot += qreg[d] * kr[d];
            int sk = (j < 64) ? (c * 64 + j) : (cm * 64 + (j - 64));
            int nk = pm[sk];
            dot = (nk == nq) ? -1e5f : dot * 0.125f;
            dotsT[j * 64 + r] = dot;
        }
    }
    __syncthreads();
    // stage values over ks
    {
        int jr = tid >> 1, hf = tid & 1;
        int sk = (jr < 64) ? (c * 64 + jr) : (cm * 64 + (jr - 64));
        int nk = pm[sk];
        const float* src = vv + (size_t)nk * 256 + h * 64 + hf * 32;
        float* dst = ks + jr * 64 + hf * 32;
#pragma unroll
        for (int d = 0; d < 32; d += 4)
            *(float4*)(dst + d) = *(const float4*)(src + d);
    }
    // softmax (one thread per row, concurrent with value staging)
    if (tid < 64) {
        int rr = tid;
        float mx = -1e30f;
        for (int j = 0; j < 128; ++j) mx = fmaxf(mx, dotsT[j * 64 + rr]);
        float s = 0.f;
        for (int j = 0; j < 128; ++j) {
            float e = expf(dotsT[j * 64 + rr] - mx);
            dotsT[j * 64 + rr] = e; s += e;
        }
        float inv = 1.f / s;
        for (int j = 0; j < 128; ++j) dotsT[j * 64 + rr] *= inv;
    }
    __syncthreads();
    // out = attn @ V ; thread covers 16 dims of its row
    int dg = jg;
    float acc[16];
#pragma unroll
    for (int d = 0; d < 16; ++d) acc[d] = 0.f;
    for (int j = 0; j < 128; ++j) {
        float a = dotsT[j * 64 + r];
        const float* vr = ks + j * 64 + dg * 16;  // j,dg uniform per wave
#pragma unroll
        for (int d = 0; d < 16; ++d) acc[d] += a * vr[d];
    }
    float* dst = o + (size_t)nq * 256 + h * 64 + dg * 16;
#pragma unroll
    for (int d = 0; d < 16; d += 4) {
        float4 v = { acc[d], acc[d + 1], acc[d + 2], acc[d + 3] };
        *(float4*)(dst + d) = v;
    }
}

// ---------------------------------------------------------------------------
extern "C" void kernel_launch(void* const* d_in, const int* in_sizes, int n_in,
                              void* d_out, int out_size, void* d_ws, size_t ws_size,
                              hipStream_t stream)
{
    const float* burst   = (const float*)d_in[0];
    const float* conv1_w = (const float*)d_in[1];  const float* conv1_b = (const float*)d_in[2];
    const float* conv2_w = (const float*)d_in[3];  const float* conv2_b = (const float*)d_in[4];
    const float* conv3_w = (const float*)d_in[5];  const float* conv3_b = (const float*)d_in[6];
    const float* ln1_g   = (const float*)d_in[7];  const float* ln1_b   = (const float*)d_in[8];
    const float* Wqk     = (const float*)d_in[9];  const float* bqk     = (const float*)d_in[10];
    const float* Wv      = (const float*)d_in[11]; const float* bvv     = (const float*)d_in[12];
    const float* Wo      = (const float*)d_in[13]; const float* bo      = (const float*)d_in[14];
    const float* rot     = (const float*)d_in[15];
    const float* ln2_g   = (const float*)d_in[16]; const float* ln2_b   = (const float*)d_in[17];
    const float* Wff1    = (const float*)d_in[18]; const float* bff1    = (const float*)d_in[19];
    const float* Wff2    = (const float*)d_in[20]; const float* bff2    = (const float*)d_in[21];
    const float* up1_w   = (const float*)d_in[22]; const float* up1_b   = (const float*)d_in[23];
    const float* dec1_w  = (const float*)d_in[24]; const float* dec1_b  = (const float*)d_in[25];
    const float* up2_w   = (const float*)d_in[26]; const float* up2_b   = (const float*)d_in[27];
    const float* dec2_w  = (const float*)d_in[28]; const float* dec2_b  = (const float*)d_in[29];
    const float* out_w   = (const float*)d_in[30]; const float* out_b   = (const float*)d_in[31];

    float* ws = (float*)d_ws;
    // workspace layout (float offsets)
    float* e1   = ws + 0;          // 64*256*256   = 4194304
    float* e2   = ws + 4194304;    // 128*128*128  = 2097152
    float* p1   = ws + 6291456;    // 64*128*128   = 1048576
    float* p2   = ws + 7340032;    // 128*64*64    = 524288
    float* seq  = ws + 7864320;    // 4096*256     = 1048576
    float* xn   = ws + 8912896;    // 1048576
    float* qkb  = ws + 9961472;    // 1048576
    float* vvb  = ws + 11010048;   // 1048576
    float* oob  = ws + 12058624;   // 1048576
    float* hdn  = ws + 13107200;   // 4096*1024    = 4194304
    float* knb  = ws + 17301504;   // 16384
    int*   buckets = (int*)(ws + 17317888);  // 16384
    int*   perm    = (int*)(ws + 17334272);  // 16384
    // aliases (lifetimes verified): d1 over xn+qkb, d1c over vvb+oob,
    // d2 over hdn, d2c over e2+p1+p2+seq.
    float* d1  = xn;
    float* d1c = vvb;
    float* d2  = hdn;
    float* d2c = e2;

    dim3 b16(16, 16);

    // encoder (frame 0 of the burst only)
    conv3x3_kernel<8><<<dim3(16, 16, 8), b16, 0, stream>>>(
        burst, 3, nullptr, 0, conv1_w, conv1_b, e1, 256, 256, 64, 1, 0);
    maxpool_kernel<<<4096, 256, 0, stream>>>(e1, p1, 64, 256, 256);
    conv3x3_kernel<8><<<dim3(8, 8, 16), b16, 0, stream>>>(
        p1, 64, nullptr, 0, conv2_w, conv2_b, e2, 128, 128, 128, 1, 0);
    maxpool_kernel<<<2048, 256, 0, stream>>>(e2, p2, 128, 128, 128);
    conv3x3_kernel<8><<<dim3(4, 4, 32), b16, 0, stream>>>(
        p2, 128, nullptr, 0, conv3_w, conv3_b, seq, 64, 64, 256, 1, 1);  // NHWC -> tokens

    // reformer, 4 layers
    for (int i = 0; i < 4; ++i) {
        ln_kernel<<<1024, 256, 0, stream>>>(seq, ln1_g + i * 256, ln1_b + i * 256, xn);
        gemm_kernel<<<dim3(4, 64), 256, 0, stream>>>(xn, Wqk + i * 65536, bqk + i * 256,
                                                     qkb, 4096, 256, 256, 0, 0);
        gemm_kernel<<<dim3(4, 64), 256, 0, stream>>>(xn, Wv + i * 65536, bvv + i * 256,
                                                     vvb, 4096, 256, 256, 0, 0);
        knorm_kernel<<<64, 256, 0, stream>>>(qkb, knb);
        bucket_kernel<<<64, 256, 0, stream>>>(qkb, rot + i * 8192, buckets);
        lsh_sort_kernel<<<4, 256, 0, stream>>>(buckets, perm);
        attn_kernel<<<dim3(64, 4), 256, 0, stream>>>(qkb, vvb, knb, perm, oob);
        gemm_kernel<<<dim3(4, 64), 256, 0, stream>>>(oob, Wo + i * 65536, bo + i * 256,
                                                     seq, 4096, 256, 256, 0, 1);  // residual
        ln_kernel<<<1024, 256, 0, stream>>>(seq, ln2_g + i * 256, ln2_b + i * 256, xn);
        gemm_kernel<<<dim3(16, 64), 256, 0, stream>>>(xn, Wff1 + i * 262144, bff1 + i * 1024,
                                                      hdn, 4096, 1024, 256, 1, 0);  // gelu
        gemm_kernel<<<dim3(4, 64), 256, 0, stream>>>(hdn, Wff2 + i * 262144, bff2 + i * 256,
                                                     seq, 4096, 256, 1024, 0, 1);  // residual
    }

    // decoder
    convt4x4_kernel<8><<<dim3(4, 4, 64), b16, 0, stream>>>(
        seq, 256, up1_w, up1_b, d1, 64, 64, 128, 1);               // NHWC input
    conv3x3_kernel<8><<<dim3(8, 8, 16), b16, 0, stream>>>(
        d1, 128, e2, 128, dec1_w, dec1_b, d1c, 128, 128, 128, 1, 0);
    convt4x4_kernel<8><<<dim3(8, 8, 32), b16, 0, stream>>>(
        d1c, 128, up2_w, up2_b, d2, 128, 128, 64, 0);
    conv3x3_kernel<8><<<dim3(16, 16, 8), b16, 0, stream>>>(
        d2, 64, e1, 64, dec2_w, dec2_b, d2c, 256, 256, 64, 1, 0);
    conv3x3_kernel<3><<<dim3(16, 16, 1), b16, 0, stream>>>(
        d2c, 64, nullptr, 0, out_w, out_b, (float*)d_out, 256, 256, 3, 2, 0);
}

// Round 3
// 1595.375 us; speedup vs baseline: 1.9196x; 1.9196x over previous
//
#include <hip/hip_runtime.h>
#include <hip/hip_bf16.h>
#include <math.h>

using short8  = __attribute__((ext_vector_type(8))) short;
using half8   = __attribute__((ext_vector_type(8))) _Float16;
using floatx4 = __attribute__((ext_vector_type(4))) float;

static __device__ __forceinline__ float gelu_f(float x) {
    float x3 = x * x * x;
    return 0.5f * x * (1.f + tanhf(0.7978845608028654f * (x + 0.044715f * x3)));
}

static __device__ __forceinline__ short f2h(float f) {
    _Float16 h = (_Float16)f;   // RNE
    return __builtin_bit_cast(short, h);
}

// ============================================================================
// FP32 KERNELS (bucket-critical path — numerically identical to round 1)
// ============================================================================

template <int OCB>
__global__ __launch_bounds__(256) void conv3x3_kernel(
    const float* __restrict__ in1, int C1, const float* __restrict__ in2, int C2,
    const float* __restrict__ w, const float* __restrict__ bias,
    float* __restrict__ out, int H, int W, int OC, int act, int nhwc_out)
{
    int tx = threadIdx.x, ty = threadIdx.y;
    int x = blockIdx.x * 16 + tx, y = blockIdx.y * 16 + ty;
    int oc0 = blockIdx.z * OCB;
    int C = C1 + C2;
    float acc[OCB];
#pragma unroll
    for (int o = 0; o < OCB; ++o) acc[o] = 0.f;
    for (int ic = 0; ic < C; ++ic) {
        const float* src = (ic < C1) ? (in1 + (size_t)ic * H * W)
                                     : (in2 + (size_t)(ic - C1) * H * W);
        float v[9];
#pragma unroll
        for (int ky = 0; ky < 3; ++ky) {
            int iy = y + ky - 1;
            bool okY = (iy >= 0) && (iy < H);
#pragma unroll
            for (int kx = 0; kx < 3; ++kx) {
                int ix = x + kx - 1;
                bool ok = okY && (ix >= 0) && (ix < W);
                v[ky * 3 + kx] = ok ? src[(size_t)iy * W + ix] : 0.f;
            }
        }
        const float* wp = w + ((size_t)oc0 * C + ic) * 9;
#pragma unroll
        for (int o = 0; o < OCB; ++o) {
            const float* wo = wp + (size_t)o * C * 9;
            acc[o] += v[0]*wo[0] + v[1]*wo[1] + v[2]*wo[2]
                    + v[3]*wo[3] + v[4]*wo[4] + v[5]*wo[5]
                    + v[6]*wo[6] + v[7]*wo[7] + v[8]*wo[8];
        }
    }
#pragma unroll
    for (int o = 0; o < OCB; ++o) {
        int oc = oc0 + o;
        float r = acc[o] + bias[oc];
        if (act == 1) r = fmaxf(r, 0.f);
        else if (act == 2) r = 1.f / (1.f + expf(-r));
        if (nhwc_out) out[(size_t)(y * W + x) * OC + oc] = r;
        else          out[(size_t)oc * H * W + (size_t)y * W + x] = r;
    }
}

__global__ __launch_bounds__(256) void maxpool_kernel(
    const float* __restrict__ in, float* __restrict__ out, int C, int IH, int IW)
{
    int OH = IH >> 1, OW = IW >> 1;
    int idx = blockIdx.x * 256 + threadIdx.x;
    int total = C * OH * OW;
    if (idx >= total) return;
    int x = idx % OW; int t = idx / OW; int y = t % OH; int c = t / OH;
    const float* p = in + (size_t)c * IH * IW + (size_t)(2 * y) * IW + 2 * x;
    out[idx] = fmaxf(fmaxf(p[0], p[1]), fmaxf(p[IW], p[IW + 1]));
}

// LayerNorm: fp32 outputs unchanged + fp16 dual-write for the MFMA consumers.
__global__ __launch_bounds__(256) void ln_kernel(
    const float* __restrict__ x, const float* __restrict__ g,
    const float* __restrict__ b, float* __restrict__ y, short* __restrict__ yh)
{
    int wave = threadIdx.x >> 6, lane = threadIdx.x & 63;
    int n = blockIdx.x * 4 + wave;
    const float* xr = x + (size_t)n * 256;
    float4 v = *(const float4*)(xr + lane * 4);
    float s = v.x + v.y + v.z + v.w;
#pragma unroll
    for (int m = 1; m < 64; m <<= 1) s += __shfl_xor(s, m);
    float mean = s * (1.f / 256.f);
    float cx = v.x - mean, cy = v.y - mean, cz = v.z - mean, cw = v.w - mean;
    float q = cx * cx + cy * cy + cz * cz + cw * cw;
#pragma unroll
    for (int m = 1; m < 64; m <<= 1) q += __shfl_xor(q, m);
    float rstd = rsqrtf(q * (1.f / 256.f) + 1e-5f);
    float4 gv = *(const float4*)(g + lane * 4);
    float4 bv = *(const float4*)(b + lane * 4);
    float4 o;
    o.x = cx * rstd * gv.x + bv.x;
    o.y = cy * rstd * gv.y + bv.y;
    o.z = cz * rstd * gv.z + bv.z;
    o.w = cw * rstd * gv.w + bv.w;
    *(float4*)(y + (size_t)n * 256 + lane * 4) = o;
    short* yp = yh + (size_t)n * 256 + lane * 4;
    yp[0] = f2h(o.x); yp[1] = f2h(o.y); yp[2] = f2h(o.z); yp[3] = f2h(o.w);
}

__global__ __launch_bounds__(256) void gemm_kernel(
    const float* __restrict__ A, const float* __restrict__ W,
    const float* __restrict__ bias, float* __restrict__ C,
    int M, int N, int K, int act, int resid)
{
    __shared__ float As[64][17];
    __shared__ float Ws[16][64];
    int tid = threadIdx.x;
    int tx = tid & 15, ty = tid >> 4;
    int m0 = blockIdx.y * 64, n0 = blockIdx.x * 64;
    int la_m = tid >> 2, la_k = (tid & 3) * 4;
    int lw_k = tid >> 4, lw_n = (tid & 15) * 4;
    float acc[4][4];
#pragma unroll
    for (int i = 0; i < 4; ++i)
#pragma unroll
        for (int j = 0; j < 4; ++j) acc[i][j] = 0.f;
    for (int k0 = 0; k0 < K; k0 += 16) {
        float4 av = *(const float4*)(A + (size_t)(m0 + la_m) * K + k0 + la_k);
        float4 wv = *(const float4*)(W + (size_t)(k0 + lw_k) * N + n0 + lw_n);
        As[la_m][la_k + 0] = av.x; As[la_m][la_k + 1] = av.y;
        As[la_m][la_k + 2] = av.z; As[la_m][la_k + 3] = av.w;
        *(float4*)(&Ws[lw_k][lw_n]) = wv;
        __syncthreads();
#pragma unroll
        for (int kk = 0; kk < 16; ++kk) {
            float a0 = As[ty * 4 + 0][kk], a1 = As[ty * 4 + 1][kk];
            float a2 = As[ty * 4 + 2][kk], a3 = As[ty * 4 + 3][kk];
            float4 wq = *(const float4*)(&Ws[kk][tx * 4]);
            acc[0][0] += a0 * wq.x; acc[0][1] += a0 * wq.y; acc[0][2] += a0 * wq.z; acc[0][3] += a0 * wq.w;
            acc[1][0] += a1 * wq.x; acc[1][1] += a1 * wq.y; acc[1][2] += a1 * wq.z; acc[1][3] += a1 * wq.w;
            acc[2][0] += a2 * wq.x; acc[2][1] += a2 * wq.y; acc[2][2] += a2 * wq.z; acc[2][3] += a2 * wq.w;
            acc[3][0] += a3 * wq.x; acc[3][1] += a3 * wq.y; acc[3][2] += a3 * wq.z; acc[3][3] += a3 * wq.w;
        }
        __syncthreads();
    }
#pragma unroll
    for (int i = 0; i < 4; ++i) {
        int cm = m0 + ty * 4 + i;
#pragma unroll
        for (int j = 0; j < 4; ++j) {
            int cn = n0 + tx * 4 + j;
            float v = acc[i][j] + bias[cn];
            if (act == 1) v = gelu_f(v);
            float* cp = C + (size_t)cm * N + cn;
            if (resid) v += *cp;
            *cp = v;
        }
    }
}

__global__ __launch_bounds__(256) void knorm_kernel(
    const float* __restrict__ qk, float* __restrict__ knrm)
{
    int t = blockIdx.x * 256 + threadIdx.x;
    int h = t >> 12, n = t & 4095;
    const float* q = qk + (size_t)n * 256 + h * 64;
    float s = 0.f;
#pragma unroll
    for (int d = 0; d < 64; d += 4) {
        float4 v = *(const float4*)(q + d);
        s += v.x * v.x + v.y * v.y + v.z * v.z + v.w * v.w;
    }
    knrm[t] = 1.f / (sqrtf(s) + 1e-6f);
}

__global__ __launch_bounds__(256) void bucket_kernel(
    const float* __restrict__ qk, const float* __restrict__ rot,
    int* __restrict__ buckets)
{
    int t = blockIdx.x * 256 + threadIdx.x;
    int h = t >> 12, n = t & 4095;
    const float* q = qk + (size_t)n * 256 + h * 64;
    const float* R = rot + (size_t)h * 2048;
    float acc[32];
#pragma unroll
    for (int r = 0; r < 32; ++r) acc[r] = 0.f;
    for (int d = 0; d < 64; ++d) {
        float qd = q[d];
        const float* Rd = R + d * 32;
#pragma unroll
        for (int r = 0; r < 32; ++r) acc[r] += qd * Rd[r];
    }
    float bvv = acc[0]; int best = 0;
#pragma unroll
    for (int j = 1; j < 64; ++j) {
        float val = (j < 32) ? acc[j] : -acc[j - 32];
        if (val > bvv) { bvv = val; best = j; }
    }
    buckets[t] = best;
}

__global__ __launch_bounds__(256) void lsh_sort_kernel(
    const int* __restrict__ buckets, int* __restrict__ perm)
{
    int h = blockIdx.x;
    const int* bk = buckets + h * 4096;
    __shared__ unsigned long long mask[64][64];
    __shared__ int counts[64];
    __shared__ int offsets[64];
    __shared__ int wpre[64][64];
    int tid = threadIdx.x, wave = tid >> 6, lane = tid & 63;
    for (int w = wave * 16; w < wave * 16 + 16; ++w) {
        int bl = bk[w * 64 + lane];
        for (int b = 0; b < 64; ++b) {
            unsigned long long m = __ballot(bl == b);
            if (lane == b) mask[b][w] = m;
        }
    }
    __syncthreads();
    if (tid < 64) {
        int c = 0;
        for (int w = 0; w < 64; ++w) c += __popcll(mask[tid][w]);
        counts[tid] = c;
    }
    __syncthreads();
    if (tid == 0) {
        int a = 0;
        for (int b = 0; b < 64; ++b) { offsets[b] = a; a += counts[b]; }
    }
    __syncthreads();
    for (int b = wave * 16; b < wave * 16 + 16; ++b) {
        int c = __popcll(mask[b][lane]);
        int incl = c;
#pragma unroll
        for (int off = 1; off < 64; off <<= 1) {
            int nb = __shfl_up(incl, off);
            if (lane >= off) incl += nb;
        }
        wpre[b][lane] = incl - c + offsets[b];
    }
    __syncthreads();
    for (int i = tid; i < 4096; i += 256) {
        int b = bk[i]; int w = i >> 6; int l = i & 63;
        unsigned long long below = mask[b][w] & ((1ull << l) - 1ull);
        int pos = wpre[b][w] + __popcll(below);
        perm[h * 4096 + pos] = i;
    }
}

// attention: fp32 path unchanged; adds fp16 dual-write of the output.
__global__ __launch_bounds__(256) void attn_kernel(
    const float* __restrict__ qk, const float* __restrict__ vv,
    const float* __restrict__ knrm, const int* __restrict__ perm,
    float* __restrict__ o, short* __restrict__ oh)
{
    __shared__ float ks[128 * 64];
    __shared__ float dotsT[128 * 64];
    int c = blockIdx.x, h = blockIdx.y;
    int tid = threadIdx.x;
    const int* pm = perm + h * 4096;
    int cm = (c + 63) & 63;
    {
        int jr = tid >> 1, hf = tid & 1;
        int sk = (jr < 64) ? (c * 64 + jr) : (cm * 64 + (jr - 64));
        int nk = pm[sk];
        float sc = knrm[h * 4096 + nk];
        const float* src = qk + (size_t)nk * 256 + h * 64 + hf * 32;
        float* dst = ks + jr * 64 + hf * 32;
#pragma unroll
        for (int d = 0; d < 32; d += 4) {
            float4 v = *(const float4*)(src + d);
            v.x *= sc; v.y *= sc; v.z *= sc; v.w *= sc;
            *(float4*)(dst + d) = v;
        }
    }
    __syncthreads();
    int r = tid & 63, jg = tid >> 6;
    int nq = pm[c * 64 + r];
    {
        float qreg[64];
        const float* src = qk + (size_t)nq * 256 + h * 64;
#pragma unroll
        for (int d = 0; d < 64; d += 4) {
            float4 v = *(const float4*)(src + d);
            qreg[d] = v.x; qreg[d + 1] = v.y; qreg[d + 2] = v.z; qreg[d + 3] = v.w;
        }
        for (int j = jg * 32; j < jg * 32 + 32; ++j) {
            const float* kr = ks + j * 64;
            float dot = 0.f;
#pragma unroll
            for (int d = 0; d < 64; ++d) dot += qreg[d] * kr[d];
            int sk = (j < 64) ? (c * 64 + j) : (cm * 64 + (j - 64));
            int nk = pm[sk];
            dot = (nk == nq) ? -1e5f : dot * 0.125f;
            dotsT[j * 64 + r] = dot;
        }
    }
    __syncthreads();
    {
        int jr = tid >> 1, hf = tid & 1;
        int sk = (jr < 64) ? (c * 64 + jr) : (cm * 64 + (jr - 64));
        int nk = pm[sk];
        const float* src = vv + (size_t)nk * 256 + h * 64 + hf * 32;
        float* dst = ks + jr * 64 + hf * 32;
#pragma unroll
        for (int d = 0; d < 32; d += 4)
            *(float4*)(dst + d) = *(const float4*)(src + d);
    }
    if (tid < 64) {
        int rr = tid;
        float mx = -1e30f;
        for (int j = 0; j < 128; ++j) mx = fmaxf(mx, dotsT[j * 64 + rr]);
        float s = 0.f;
        for (int j = 0; j < 128; ++j) {
            float e = expf(dotsT[j * 64 + rr] - mx);
            dotsT[j * 64 + rr] = e; s += e;
        }
        float inv = 1.f / s;
        for (int j = 0; j < 128; ++j) dotsT[j * 64 + rr] *= inv;
    }
    __syncthreads();
    int dg = jg;
    float acc[16];
#pragma unroll
    for (int d = 0; d < 16; ++d) acc[d] = 0.f;
    for (int j = 0; j < 128; ++j) {
        float a = dotsT[j * 64 + r];
        const float* vr = ks + j * 64 + dg * 16;
#pragma unroll
        for (int d = 0; d < 16; ++d) acc[d] += a * vr[d];
    }
    size_t ob = (size_t)nq * 256 + h * 64 + dg * 16;
    float* dst = o + ob;
    short* dsth = oh + ob;
#pragma unroll
    for (int d = 0; d < 16; d += 4) {
        float4 v = { acc[d], acc[d + 1], acc[d + 2], acc[d + 3] };
        *(float4*)(dst + d) = v;
        dsth[d] = f2h(v.x); dsth[d+1] = f2h(v.y);
        dsth[d+2] = f2h(v.z); dsth[d+3] = f2h(v.w);
    }
}

// ============================================================================
// FP16 MFMA kernels (post-bucket tail + decoder)
// Fragment layouts (guide §3, m89/m120 verified, dtype-independent):
//   A[m=lane&15][k=quad*8+j], B[k=quad*8+j][n=lane&15], C/D col=lane&15,row=quad*4+reg
// ============================================================================

// pack W[K][N] fp32 -> frag-ready fp16: Bp[(kt*NT+nt)*64+lane][8]
__global__ void pack_gemm_kernel(const float* __restrict__ W, short* __restrict__ Bp,
                                 int N, int total)
{
    int t = blockIdx.x * 256 + threadIdx.x;
    if (t >= total) return;
    int lane = t & 63, fi = t >> 6;
    int NT = N >> 4;
    int nt = fi % NT, kt = fi / NT;
    int n = nt * 16 + (lane & 15);
    int k0 = kt * 32 + (lane >> 4) * 8;
    short8 v;
#pragma unroll
    for (int j = 0; j < 8; ++j) v[j] = f2h(W[(size_t)(k0 + j) * N + n]);
    ((short8*)Bp)[t] = v;
}

// pack conv w[OC][C][3][3] fp32 -> fp16 frags, k = (ky*3+kx)*C + c
__global__ void pack_conv_kernel(const float* __restrict__ w, short* __restrict__ Bp,
                                 int C, int OC, int NT, int total)
{
    int t = blockIdx.x * 256 + threadIdx.x;
    if (t >= total) return;
    int lane = t & 63, fi = t >> 6;
    int nt = fi % NT, kt = fi / NT;
    int cpt = C >> 5;
    int tap = kt / cpt, ct = kt % cpt;
    int c = ct * 32 + (lane >> 4) * 8;
    int oc = nt * 16 + (lane & 15);
    short8 v;
#pragma unroll
    for (int j = 0; j < 8; ++j) {
        float f = (oc < OC) ? w[((size_t)oc * C + c + j) * 9 + tap] : 0.f;
        v[j] = f2h(f);
    }
    ((short8*)Bp)[t] = v;
}

// pack convT w[IC][OC][4][4] fp32 -> per-parity fp16 frags, k = (ty*2+tx)*IC + ic
__global__ void pack_convt_kernel(const float* __restrict__ w, short* __restrict__ Bp,
                                  int IC, int OC, int total)
{
    int t = blockIdx.x * 256 + threadIdx.x;
    if (t >= total) return;
    int lane = t & 63, fi = t >> 6;
    int NT = OC >> 4, cpt = IC >> 5, KT4 = 4 * cpt;
    int nt = fi % NT, r = fi / NT;
    int kt = r % KT4, pz = r / KT4;
    int py = pz >> 1, px = pz & 1;
    int t4 = kt / cpt, ct = kt % cpt;
    int ty = t4 >> 1, tx = t4 & 1;
    int ky = py ? (2 * ty) : (1 + 2 * ty);
    int kx = px ? (2 * tx) : (1 + 2 * tx);
    int ic = ct * 32 + (lane >> 4) * 8;
    int oc = nt * 16 + (lane & 15);
    short8 v;
#pragma unroll
    for (int j = 0; j < 8; ++j)
        v[j] = f2h(w[(((size_t)(ic + j) * OC + oc) * 4 + ky) * 4 + kx]);
    ((short8*)Bp)[t] = v;
}

// GEMM: out = act(A_fp16[M,K] @ Bp + bias) (+resid). out fp32 or fp16.
__global__ __launch_bounds__(256) void gemm_mfma_kernel(
    const short* __restrict__ A, const short* __restrict__ Bp,
    const float* __restrict__ bias, float* __restrict__ Cf, short* __restrict__ Cb,
    int M, int N, int K, int act, int resid)
{
    int tid = threadIdx.x, wave = tid >> 6, lane = tid & 63;
    int quad = lane >> 4, l16 = lane & 15;
    int m0 = blockIdx.y * 64 + wave * 16;
    int NT = N >> 4;
    int nt0 = blockIdx.x * 4;
    const half8* arow = (const half8*)(A + (size_t)(m0 + l16) * K + quad * 8);
    const half8* bp = (const half8*)Bp;
    floatx4 acc0 = {0,0,0,0}, acc1 = {0,0,0,0}, acc2 = {0,0,0,0}, acc3 = {0,0,0,0};
    int KT = K >> 5;
    for (int kt = 0; kt < KT; ++kt) {
        half8 a = arow[kt * 4];
        size_t bi = ((size_t)kt * NT + nt0) * 64 + lane;
        acc0 = __builtin_amdgcn_mfma_f32_16x16x32_f16(a, bp[bi      ], acc0, 0, 0, 0);
        acc1 = __builtin_amdgcn_mfma_f32_16x16x32_f16(a, bp[bi +  64], acc1, 0, 0, 0);
        acc2 = __builtin_amdgcn_mfma_f32_16x16x32_f16(a, bp[bi + 128], acc2, 0, 0, 0);
        acc3 = __builtin_amdgcn_mfma_f32_16x16x32_f16(a, bp[bi + 192], acc3, 0, 0, 0);
    }
    floatx4 accs[4] = {acc0, acc1, acc2, acc3};
#pragma unroll
    for (int s = 0; s < 4; ++s) {
        int n = (nt0 + s) * 16 + l16;
        float bs = bias[n];
#pragma unroll
        for (int r = 0; r < 4; ++r) {
            int m = m0 + quad * 4 + r;
            float v = accs[s][r] + bs;
            if (act == 1) v = gelu_f(v);
            size_t o = (size_t)m * N + n;
            if (resid) v += Cf[o];
            if (Cb) Cb[o] = f2h(v);
            else    Cf[o] = v;
        }
    }
}

// 3x3 conv (pad 1) as 9 shifted GEMM taps over NHWC fp16, relu epilogue.
__global__ __launch_bounds__(256) void conv_mfma_kernel(
    const short* __restrict__ in1, int C1, const short* __restrict__ in2, int C2,
    const short* __restrict__ Bp, const float* __restrict__ bias,
    float* __restrict__ outf, short* __restrict__ outb, int H, int W, int OC)
{
    int tid = threadIdx.x, wave = tid >> 6, lane = tid & 63;
    int quad = lane >> 4, l16 = lane & 15;
    int x0 = blockIdx.x * 64, y = blockIdx.y, nt0 = blockIdx.z * 4;
    int C = C1 + C2, cpt = C >> 5, NT = OC >> 4;
    const half8* bp = (const half8*)Bp;
    floatx4 acc0 = {0,0,0,0}, acc1 = {0,0,0,0}, acc2 = {0,0,0,0}, acc3 = {0,0,0,0};
    int xm = x0 + wave * 16 + l16;
    for (int ky = 0; ky < 3; ++ky) {
        int yy = y + ky - 1;
        bool rok = (yy >= 0) && (yy < H);
        for (int kx = 0; kx < 3; ++kx) {
            int xx = xm + kx - 1;
            bool ok = rok && (xx >= 0) && (xx < W);
            int pos = yy * W + xx;
            int ktb = (ky * 3 + kx) * cpt;
            for (int ct = 0; ct < cpt; ++ct) {
                int cc = ct * 32 + quad * 8;
                half8 a = {};
                if (ok) {
                    const short* src = (cc < C1) ? (in1 + (size_t)pos * C1 + cc)
                                                 : (in2 + (size_t)pos * C2 + (cc - C1));
                    a = *(const half8*)src;
                }
                size_t bi = ((size_t)(ktb + ct) * NT + nt0) * 64 + lane;
                acc0 = __builtin_amdgcn_mfma_f32_16x16x32_f16(a, bp[bi      ], acc0, 0, 0, 0);
                acc1 = __builtin_amdgcn_mfma_f32_16x16x32_f16(a, bp[bi +  64], acc1, 0, 0, 0);
                acc2 = __builtin_amdgcn_mfma_f32_16x16x32_f16(a, bp[bi + 128], acc2, 0, 0, 0);
                acc3 = __builtin_amdgcn_mfma_f32_16x16x32_f16(a, bp[bi + 192], acc3, 0, 0, 0);
            }
        }
    }
    floatx4 accs[4] = {acc0, acc1, acc2, acc3};
#pragma unroll
    for (int s = 0; s < 4; ++s) {
        int n = (nt0 + s) * 16 + l16;
        float bs = bias[n];
#pragma unroll
        for (int r = 0; r < 4; ++r) {
            int m = wave * 16 + quad * 4 + r;
            int x = x0 + m;
            float v = fmaxf(accs[s][r] + bs, 0.f);
            size_t o = ((size_t)y * W + x) * OC + n;
            if (outb) outb[o] = f2h(v);
            else      outf[o] = v;
        }
    }
}

// ConvTranspose2d k4 s2 p1 via per-parity 2x2-tap shifted GEMMs, NHWC fp16.
__global__ __launch_bounds__(256) void convt_mfma_kernel(
    const short* __restrict__ in, int IC, const short* __restrict__ Bp,
    const float* __restrict__ bias, short* __restrict__ outb, int IH, int IW, int OC)
{
    int tid = threadIdx.x, wave = tid >> 6, lane = tid & 63;
    int quad = lane >> 4, l16 = lane & 15;
    int pz = blockIdx.z & 3, nt0 = (blockIdx.z >> 2) * 4;
    int py = pz >> 1, px = pz & 1;
    int a0 = blockIdx.y, b0 = blockIdx.x * 64;
    int cpt = IC >> 5, NT = OC >> 4, KT4 = 4 * cpt;
    const half8* bp = (const half8*)Bp;
    floatx4 acc0 = {0,0,0,0}, acc1 = {0,0,0,0}, acc2 = {0,0,0,0}, acc3 = {0,0,0,0};
    int bm = b0 + wave * 16 + l16;
    for (int ty = 0; ty < 2; ++ty) {
        int iy = a0 + (py ? (1 - ty) : (-ty));
        bool rok = (iy >= 0) && (iy < IH);
        for (int tx = 0; tx < 2; ++tx) {
            int ix = bm + (px ? (1 - tx) : (-tx));
            bool ok = rok && (ix >= 0) && (ix < IW);
            int pos = iy * IW + ix;
            int ktb = (ty * 2 + tx) * cpt;
            for (int ct = 0; ct < cpt; ++ct) {
                int cc = ct * 32 + quad * 8;
                half8 a = {};
                if (ok) a = *(const half8*)(in + (size_t)pos * IC + cc);
                size_t bi = ((size_t)(pz * KT4 + ktb + ct) * NT + nt0) * 64 + lane;
                acc0 = __builtin_amdgcn_mfma_f32_16x16x32_f16(a, bp[bi      ], acc0, 0, 0, 0);
                acc1 = __builtin_amdgcn_mfma_f32_16x16x32_f16(a, bp[bi +  64], acc1, 0, 0, 0);
                acc2 = __builtin_amdgcn_mfma_f32_16x16x32_f16(a, bp[bi + 128], acc2, 0, 0, 0);
                acc3 = __builtin_amdgcn_mfma_f32_16x16x32_f16(a, bp[bi + 192], acc3, 0, 0, 0);
            }
        }
    }
    floatx4 accs[4] = {acc0, acc1, acc2, acc3};
    int OW = IW * 2;
    int oy = 2 * a0 + py;
#pragma unroll
    for (int s = 0; s < 4; ++s) {
        int n = (nt0 + s) * 16 + l16;
        float bs = bias[n];
#pragma unroll
        for (int r = 0; r < 4; ++r) {
            int m = wave * 16 + quad * 4 + r;
            int ox = 2 * (b0 + m) + px;
            float v = accs[s][r] + bs;
            outb[((size_t)oy * OW + ox) * OC + n] = f2h(v);
        }
    }
}

// final 3x3 conv: C=64 -> 3 channels (padded to 16), sigmoid, NCHW fp32 out.
__global__ __launch_bounds__(256) void convout_mfma_kernel(
    const short* __restrict__ in, const short* __restrict__ Bp,
    const float* __restrict__ bias, float* __restrict__ out, int H, int W)
{
    int tid = threadIdx.x, wave = tid >> 6, lane = tid & 63;
    int quad = lane >> 4, l16 = lane & 15;
    int x0 = blockIdx.x * 64, y = blockIdx.y;
    const int C = 64, cpt = 2;
    const half8* bp = (const half8*)Bp;
    floatx4 acc = {0,0,0,0};
    int xm = x0 + wave * 16 + l16;
    for (int ky = 0; ky < 3; ++ky) {
        int yy = y + ky - 1;
        bool rok = (yy >= 0) && (yy < H);
        for (int kx = 0; kx < 3; ++kx) {
            int xx = xm + kx - 1;
            bool ok = rok && (xx >= 0) && (xx < W);
            int pos = yy * W + xx;
            int ktb = (ky * 3 + kx) * cpt;
#pragma unroll
            for (int ct = 0; ct < cpt; ++ct) {
                int cc = ct * 32 + quad * 8;
                half8 a = {};
                if (ok) a = *(const half8*)(in + (size_t)pos * C + cc);
                acc = __builtin_amdgcn_mfma_f32_16x16x32_f16(
                          a, bp[(size_t)(ktb + ct) * 64 + lane], acc, 0, 0, 0);
            }
        }
    }
    int oc = l16;
    if (oc < 3) {
        float bs = bias[oc];
#pragma unroll
        for (int r = 0; r < 4; ++r) {
            int m = wave * 16 + quad * 4 + r;
            int x = x0 + m;
            float v = acc[r] + bs;
            v = 1.f / (1.f + expf(-v));
            out[(size_t)oc * H * W + (size_t)y * W + x] = v;
        }
    }
}

// NCHW fp32 -> NHWC fp16 (LDS tile transpose)
__global__ __launch_bounds__(256) void nchw2nhwc_h_kernel(
    const float* __restrict__ in, short* __restrict__ out, int C, int HW)
{
    __shared__ float t[32][33];
    int c0 = blockIdx.y * 32, p0 = blockIdx.x * 32;
    int tid = threadIdx.x;
#pragma unroll
    for (int it = 0; it < 4; ++it) {
        int i = tid + it * 256;
        int lc = i >> 5, lp = i & 31;
        t[lc][lp] = in[(size_t)(c0 + lc) * HW + p0 + lp];
    }
    __syncthreads();
#pragma unroll
    for (int it = 0; it < 4; ++it) {
        int i = tid + it * 256;
        int lp = i >> 5, lc = i & 31;
        out[(size_t)(p0 + lp) * C + c0 + lc] = f2h(t[lc][lp]);
    }
}

__global__ __launch_bounds__(256) void f2h_kernel(
    const float* __restrict__ in, short* __restrict__ out, int n)
{
    int i = blockIdx.x * 256 + threadIdx.x;
    if (i < n) out[i] = f2h(in[i]);
}

// ============================================================================
extern "C" void kernel_launch(void* const* d_in, const int* in_sizes, int n_in,
                              void* d_out, int out_size, void* d_ws, size_t ws_size,
                              hipStream_t stream)
{
    const float* burst   = (const float*)d_in[0];
    const float* conv1_w = (const float*)d_in[1];  const float* conv1_b = (const float*)d_in[2];
    const float* conv2_w = (const float*)d_in[3];  const float* conv2_b = (const float*)d_in[4];
    const float* conv3_w = (const float*)d_in[5];  const float* conv3_b = (const float*)d_in[6];
    const float* ln1_g   = (const float*)d_in[7];  const float* ln1_b   = (const float*)d_in[8];
    const float* Wqk     = (const float*)d_in[9];  const float* bqk     = (const float*)d_in[10];
    const float* Wv      = (const float*)d_in[11]; const float* bvv     = (const float*)d_in[12];
    const float* Wo      = (const float*)d_in[13]; const float* bo      = (const float*)d_in[14];
    const float* rot     = (const float*)d_in[15];
    const float* ln2_g   = (const float*)d_in[16]; const float* ln2_b   = (const float*)d_in[17];
    const float* Wff1    = (const float*)d_in[18]; const float* bff1    = (const float*)d_in[19];
    const float* Wff2    = (const float*)d_in[20]; const float* bff2    = (const float*)d_in[21];
    const float* up1_w   = (const float*)d_in[22]; const float* up1_b   = (const float*)d_in[23];
    const float* dec1_w  = (const float*)d_in[24]; const float* dec1_b  = (const float*)d_in[25];
    const float* up2_w   = (const float*)d_in[26]; const float* up2_b   = (const float*)d_in[27];
    const float* dec2_w  = (const float*)d_in[28]; const float* dec2_b  = (const float*)d_in[29];
    const float* out_w   = (const float*)d_in[30]; const float* out_b   = (const float*)d_in[31];

    float* ws = (float*)d_ws;
    // fp32 regions
    float* e1   = ws + 0;          // 64*256*256
    float* e2   = ws + 4194304;    // 128*128*128
    float* p1   = ws + 6291456;    // 64*128*128   (dead after conv2)
    float* p2   = ws + 7340032;    // 128*64*64    (dead after conv3)
    float* seq  = ws + 7864320;    // 4096*256
    float* xn   = ws + 8912896;
    float* qkb  = ws + 9961472;
    float* vvb  = ws + 11010048;
    float* oob  = ws + 12058624;
    float* hdn  = ws + 13107200;   // 4096*1024 (layers 0-2)
    float* knb  = ws + 17301504;
    int* buckets = (int*)(ws + 17317888);
    int* perm    = (int*)(ws + 17334272);
    // fp16 regions aliased into dead fp32 space
    short* xnh  = (short*)p1;                    // 4096*256 h (over p1 lower half)
    short* seqh = (short*)(ws + 6815744);        // 4096*256 h (over p1 upper half)
    short* ooh  = (short*)p2;                    // 4096*256 h
    short* hdnh = (short*)hdn;                   // 4096*1024 h (layer 3)
    short* e1h  = (short*)(ws + 15204352);       // 65536*64 h (over hdn upper half)
    short* e2h  = (short*)vvb;                   // 16384*128 h (after layer-3 attn)
    short* d1   = (short*)xn;                    // 16384*128 h
    short* d1c  = (short*)qkb;                   // 16384*128 h
    short* d2   = (short*)hdn;                   // 65536*64 h
    short* d2c  = (short*)e2;                    // 65536*64 h
    // weight packs (fresh space at end)
    short* pk    = (short*)(ws + 17350656);
    short* ppv   = pk;             // 65536
    short* ppo   = pk + 65536;     // 65536
    short* ppf1  = pk + 131072;    // 262144
    short* ppf2  = pk + 393216;    // 262144
    short* pdec1 = pk + 655360;    // 294912
    short* pdec2 = pk + 950272;    // 73728
    short* pout  = pk + 1024000;   // 9216
    short* pup1  = pk + 1033216;   // 524288
    short* pup2  = pk + 1557504;   // 131072

    dim3 b16(16, 16);

    // ---- weight packing (layer-3 tail + decoder)
    pack_gemm_kernel<<<32, 256, 0, stream>>>(Wv  + 3 * 65536,  ppv,  256, 8192);
    pack_gemm_kernel<<<32, 256, 0, stream>>>(Wo  + 3 * 65536,  ppo,  256, 8192);
    pack_gemm_kernel<<<128, 256, 0, stream>>>(Wff1 + 3 * 262144, ppf1, 1024, 32768);
    pack_gemm_kernel<<<128, 256, 0, stream>>>(Wff2 + 3 * 262144, ppf2, 256, 32768);
    pack_conv_kernel<<<144, 256, 0, stream>>>(dec1_w, pdec1, 256, 128, 8, 36864);
    pack_conv_kernel<<<36, 256, 0, stream>>>(dec2_w, pdec2, 128, 64, 4, 9216);
    pack_conv_kernel<<<5, 256, 0, stream>>>(out_w,  pout,  64, 3, 1, 1152);
    pack_convt_kernel<<<256, 256, 0, stream>>>(up1_w, pup1, 256, 128, 65536);
    pack_convt_kernel<<<64, 256, 0, stream>>>(up2_w, pup2, 128, 64, 16384);

    // ---- encoder (fp32 path, bucket-critical)
    conv3x3_kernel<8><<<dim3(16, 16, 8), b16, 0, stream>>>(
        burst, 3, nullptr, 0, conv1_w, conv1_b, e1, 256, 256, 64, 1, 0);
    maxpool_kernel<<<4096, 256, 0, stream>>>(e1, p1, 64, 256, 256);
    conv3x3_kernel<8><<<dim3(8, 8, 16), b16, 0, stream>>>(
        p1, 64, nullptr, 0, conv2_w, conv2_b, e2, 128, 128, 128, 1, 0);
    maxpool_kernel<<<2048, 256, 0, stream>>>(e2, p2, 128, 128, 128);
    conv3x3_kernel<8><<<dim3(4, 4, 32), b16, 0, stream>>>(
        p2, 128, nullptr, 0, conv3_w, conv3_b, seq, 64, 64, 256, 1, 1);

    // ---- reformer layers 0-2 (fp32 path, bucket-critical)
    for (int i = 0; i < 3; ++i) {
        ln_kernel<<<1024, 256, 0, stream>>>(seq, ln1_g + i * 256, ln1_b + i * 256, xn, xnh);
        gemm_kernel<<<dim3(4, 64), 256, 0, stream>>>(xn, Wqk + i * 65536, bqk + i * 256,
                                                     qkb, 4096, 256, 256, 0, 0);
        gemm_kernel<<<dim3(4, 64), 256, 0, stream>>>(xn, Wv + i * 65536, bvv + i * 256,
                                                     vvb, 4096, 256, 256, 0, 0);
        knorm_kernel<<<64, 256, 0, stream>>>(qkb, knb);
        bucket_kernel<<<64, 256, 0, stream>>>(qkb, rot + i * 8192, buckets);
        lsh_sort_kernel<<<4, 256, 0, stream>>>(buckets, perm);
        attn_kernel<<<dim3(64, 4), 256, 0, stream>>>(qkb, vvb, knb, perm, oob, ooh);
        gemm_kernel<<<dim3(4, 64), 256, 0, stream>>>(oob, Wo + i * 65536, bo + i * 256,
                                                     seq, 4096, 256, 256, 0, 1);
        ln_kernel<<<1024, 256, 0, stream>>>(seq, ln2_g + i * 256, ln2_b + i * 256, xn, xnh);
        gemm_kernel<<<dim3(16, 64), 256, 0, stream>>>(xn, Wff1 + i * 262144, bff1 + i * 1024,
                                                      hdn, 4096, 1024, 256, 1, 0);
        gemm_kernel<<<dim3(4, 64), 256, 0, stream>>>(hdn, Wff2 + i * 262144, bff2 + i * 256,
                                                     seq, 4096, 256, 1024, 0, 1);
    }

    // ---- layer 3: fp32 QK (bucket path) + fp16 MFMA tail
    {
        const int i = 3;
        ln_kernel<<<1024, 256, 0, stream>>>(seq, ln1_g + i * 256, ln1_b + i * 256, xn, xnh);
        gemm_kernel<<<dim3(4, 64), 256, 0, stream>>>(xn, Wqk + i * 65536, bqk + i * 256,
                                                     qkb, 4096, 256, 256, 0, 0);
        gemm_mfma_kernel<<<dim3(4, 64), 256, 0, stream>>>(
            xnh, ppv, bvv + i * 256, vvb, nullptr, 4096, 256, 256, 0, 0);
        knorm_kernel<<<64, 256, 0, stream>>>(qkb, knb);
        bucket_kernel<<<64, 256, 0, stream>>>(qkb, rot + i * 8192, buckets);
        lsh_sort_kernel<<<4, 256, 0, stream>>>(buckets, perm);
        attn_kernel<<<dim3(64, 4), 256, 0, stream>>>(qkb, vvb, knb, perm, oob, ooh);
        gemm_mfma_kernel<<<dim3(4, 64), 256, 0, stream>>>(
            ooh, ppo, bo + i * 256, seq, nullptr, 4096, 256, 256, 0, 1);
        ln_kernel<<<1024, 256, 0, stream>>>(seq, ln2_g + i * 256, ln2_b + i * 256, xn, xnh);
        gemm_mfma_kernel<<<dim3(16, 64), 256, 0, stream>>>(
            xnh, ppf1, bff1 + i * 1024, nullptr, hdnh, 4096, 1024, 256, 1, 0);
        gemm_mfma_kernel<<<dim3(4, 64), 256, 0, stream>>>(
            hdnh, ppf2, bff2 + i * 256, seq, nullptr, 4096, 256, 1024, 0, 1);
    }

    // ---- layout conversions for the MFMA decoder
    nchw2nhwc_h_kernel<<<dim3(2048, 2), 256, 0, stream>>>(e1, e1h, 64, 65536);
    nchw2nhwc_h_kernel<<<dim3(512, 4), 256, 0, stream>>>(e2, e2h, 128, 16384);
    f2h_kernel<<<4096, 256, 0, stream>>>(seq, seqh, 1048576);

    // ---- decoder (fp16 MFMA)
    convt_mfma_kernel<<<dim3(1, 64, 8), 256, 0, stream>>>(
        seqh, 256, pup1, up1_b, d1, 64, 64, 128);
    conv_mfma_kernel<<<dim3(2, 128, 2), 256, 0, stream>>>(
        d1, 128, e2h, 128, pdec1, dec1_b, nullptr, d1c, 128, 128, 128);
    convt_mfma_kernel<<<dim3(2, 128, 4), 256, 0, stream>>>(
        d1c, 128, pup2, up2_b, d2, 128, 128, 64);
    conv_mfma_kernel<<<dim3(4, 256, 1), 256, 0, stream>>>(
        d2, 64, e1h, 64, pdec2, dec2_b, nullptr, d2c, 256, 256, 64);
    convout_mfma_kernel<<<dim3(4, 256), 256, 0, stream>>>(
        d2c, pout, out_b, (float*)d_out, 256, 256);
}

// Round 4
// 1431.241 us; speedup vs baseline: 2.1397x; 1.1147x over previous
//
#include <hip/hip_runtime.h>
#include <hip/hip_bf16.h>
#include <math.h>

using short8  = __attribute__((ext_vector_type(8))) short;
using half8   = __attribute__((ext_vector_type(8))) _Float16;
using floatx4 = __attribute__((ext_vector_type(4))) float;

static __device__ __forceinline__ float gelu_f(float x) {
    float x3 = x * x * x;
    return 0.5f * x * (1.f + tanhf(0.7978845608028654f * (x + 0.044715f * x3)));
}

static __device__ __forceinline__ short f2h(float f) {
    _Float16 h = (_Float16)f;   // RNE
    return __builtin_bit_cast(short, h);
}

// ============================================================================
// FP32 KERNELS (bucket-critical path)
// ============================================================================

// conv1 only (C=3): original direct conv
template <int OCB>
__global__ __launch_bounds__(256) void conv3x3_kernel(
    const float* __restrict__ in1, int C1, const float* __restrict__ in2, int C2,
    const float* __restrict__ w, const float* __restrict__ bias,
    float* __restrict__ out, int H, int W, int OC, int act, int nhwc_out)
{
    int tx = threadIdx.x, ty = threadIdx.y;
    int x = blockIdx.x * 16 + tx, y = blockIdx.y * 16 + ty;
    int oc0 = blockIdx.z * OCB;
    int C = C1 + C2;
    float acc[OCB];
#pragma unroll
    for (int o = 0; o < OCB; ++o) acc[o] = 0.f;
    for (int ic = 0; ic < C; ++ic) {
        const float* src = (ic < C1) ? (in1 + (size_t)ic * H * W)
                                     : (in2 + (size_t)(ic - C1) * H * W);
        float v[9];
#pragma unroll
        for (int ky = 0; ky < 3; ++ky) {
            int iy = y + ky - 1;
            bool okY = (iy >= 0) && (iy < H);
#pragma unroll
            for (int kx = 0; kx < 3; ++kx) {
                int ix = x + kx - 1;
                bool ok = okY && (ix >= 0) && (ix < W);
                v[ky * 3 + kx] = ok ? src[(size_t)iy * W + ix] : 0.f;
            }
        }
        const float* wp = w + ((size_t)oc0 * C + ic) * 9;
#pragma unroll
        for (int o = 0; o < OCB; ++o) {
            const float* wo = wp + (size_t)o * C * 9;
            acc[o] += v[0]*wo[0] + v[1]*wo[1] + v[2]*wo[2]
                    + v[3]*wo[3] + v[4]*wo[4] + v[5]*wo[5]
                    + v[6]*wo[6] + v[7]*wo[7] + v[8]*wo[8];
        }
    }
#pragma unroll
    for (int o = 0; o < OCB; ++o) {
        int oc = oc0 + o;
        float r = acc[o] + bias[oc];
        if (act == 1) r = fmaxf(r, 0.f);
        else if (act == 2) r = 1.f / (1.f + expf(-r));
        if (nhwc_out) out[(size_t)(y * W + x) * OC + oc] = r;
        else          out[(size_t)oc * H * W + (size_t)y * W + x] = r;
    }
}

// conv2/conv3: LDS-staged input (16-channel chunks), same accumulation order.
__global__ __launch_bounds__(256) void conv3x3_lds_kernel(
    const float* __restrict__ in, const float* __restrict__ w,
    const float* __restrict__ bias, float* __restrict__ out,
    int H, int W, int C, int OC, int nhwc_out)
{
    __shared__ float s[16 * 324];   // [ic][18][18]
    int tid = threadIdx.x;
    int tx = tid & 15, ty = tid >> 4;
    int x0 = blockIdx.x * 16, y0 = blockIdx.y * 16;
    int oc0 = blockIdx.z * 8;
    int HW = H * W;
    float acc[8];
#pragma unroll
    for (int o = 0; o < 8; ++o) acc[o] = 0.f;
    for (int ic0 = 0; ic0 < C; ic0 += 16) {
        __syncthreads();
        for (int idx = tid; idx < 16 * 324; idx += 256) {
            int ic = idx / 324;
            int r = idx - ic * 324;
            int yy = r / 18;
            int xx = r - yy * 18;
            int gy = y0 + yy - 1, gx = x0 + xx - 1;
            float v = 0.f;
            if (gy >= 0 && gy < H && gx >= 0 && gx < W)
                v = in[(size_t)(ic0 + ic) * HW + (size_t)gy * W + gx];
            s[idx] = v;
        }
        __syncthreads();
        for (int ic = 0; ic < 16; ++ic) {
            const float* sc = s + ic * 324;
            float v[9];
            v[0] = sc[(ty + 0) * 18 + tx + 0];
            v[1] = sc[(ty + 0) * 18 + tx + 1];
            v[2] = sc[(ty + 0) * 18 + tx + 2];
            v[3] = sc[(ty + 1) * 18 + tx + 0];
            v[4] = sc[(ty + 1) * 18 + tx + 1];
            v[5] = sc[(ty + 1) * 18 + tx + 2];
            v[6] = sc[(ty + 2) * 18 + tx + 0];
            v[7] = sc[(ty + 2) * 18 + tx + 1];
            v[8] = sc[(ty + 2) * 18 + tx + 2];
            const float* wp = w + ((size_t)oc0 * C + ic0 + ic) * 9;
#pragma unroll
            for (int o = 0; o < 8; ++o) {
                const float* wo = wp + (size_t)o * C * 9;
                acc[o] += v[0]*wo[0] + v[1]*wo[1] + v[2]*wo[2]
                        + v[3]*wo[3] + v[4]*wo[4] + v[5]*wo[5]
                        + v[6]*wo[6] + v[7]*wo[7] + v[8]*wo[8];
            }
        }
    }
    int x = x0 + tx, y = y0 + ty;
#pragma unroll
    for (int o = 0; o < 8; ++o) {
        int oc = oc0 + o;
        float r = fmaxf(acc[o] + bias[oc], 0.f);
        if (nhwc_out) out[(size_t)(y * W + x) * OC + oc] = r;
        else          out[(size_t)oc * HW + (size_t)y * W + x] = r;
    }
}

__global__ __launch_bounds__(256) void maxpool_kernel(
    const float* __restrict__ in, float* __restrict__ out, int C, int IH, int IW)
{
    int OH = IH >> 1, OW = IW >> 1;
    int idx = blockIdx.x * 256 + threadIdx.x;
    int total = C * OH * OW;
    if (idx >= total) return;
    int x = idx % OW; int t = idx / OW; int y = t % OH; int c = t / OH;
    const float* p = in + (size_t)c * IH * IW + (size_t)(2 * y) * IW + 2 * x;
    out[idx] = fmaxf(fmaxf(p[0], p[1]), fmaxf(p[IW], p[IW + 1]));
}

// LayerNorm: fp32 outputs + fp16 dual-write for MFMA consumers.
__global__ __launch_bounds__(256) void ln_kernel(
    const float* __restrict__ x, const float* __restrict__ g,
    const float* __restrict__ b, float* __restrict__ y, short* __restrict__ yh)
{
    int wave = threadIdx.x >> 6, lane = threadIdx.x & 63;
    int n = blockIdx.x * 4 + wave;
    const float* xr = x + (size_t)n * 256;
    float4 v = *(const float4*)(xr + lane * 4);
    float s = v.x + v.y + v.z + v.w;
#pragma unroll
    for (int m = 1; m < 64; m <<= 1) s += __shfl_xor(s, m);
    float mean = s * (1.f / 256.f);
    float cx = v.x - mean, cy = v.y - mean, cz = v.z - mean, cw = v.w - mean;
    float q = cx * cx + cy * cy + cz * cz + cw * cw;
#pragma unroll
    for (int m = 1; m < 64; m <<= 1) q += __shfl_xor(q, m);
    float rstd = rsqrtf(q * (1.f / 256.f) + 1e-5f);
    float4 gv = *(const float4*)(g + lane * 4);
    float4 bv = *(const float4*)(b + lane * 4);
    float4 o;
    o.x = cx * rstd * gv.x + bv.x;
    o.y = cy * rstd * gv.y + bv.y;
    o.z = cz * rstd * gv.z + bv.z;
    o.w = cw * rstd * gv.w + bv.w;
    *(float4*)(y + (size_t)n * 256 + lane * 4) = o;
    short* yp = yh + (size_t)n * 256 + lane * 4;
    yp[0] = f2h(o.x); yp[1] = f2h(o.y); yp[2] = f2h(o.z); yp[3] = f2h(o.w);
}

// fp32 GEMM core: 64x64 tile, As transposed [k][m], register prefetch.
// Accumulation order per output element identical to round-1 (k ascending).
static __device__ __forceinline__ void gemm_core(
    const float* __restrict__ A, const float* __restrict__ W,
    const float* __restrict__ bias, float* __restrict__ Cp,
    int N, int K, int act, int resid, int m0, int n0)
{
    __shared__ float As[16][68];
    __shared__ float Ws[16][68];
    int tid = threadIdx.x;
    int tx = tid & 15, ty = tid >> 4;
    int lm = tid & 63, lk = (tid >> 6) * 4;
    int lwk = tid >> 4, lwn = (tid & 15) * 4;
    const float* Ap = A + (size_t)(m0 + lm) * K + lk;
    const float* Wp = W + (size_t)lwk * N + n0 + lwn;
    float4 av = *(const float4*)Ap;
    float4 wv = *(const float4*)Wp;
    float acc[4][4];
#pragma unroll
    for (int i = 0; i < 4; ++i)
#pragma unroll
        for (int j = 0; j < 4; ++j) acc[i][j] = 0.f;
    for (int k0 = 0; k0 < K; k0 += 16) {
        As[lk + 0][lm] = av.x; As[lk + 1][lm] = av.y;
        As[lk + 2][lm] = av.z; As[lk + 3][lm] = av.w;
        *(float4*)(&Ws[lwk][lwn]) = wv;
        __syncthreads();
        if (k0 + 16 < K) {
            av = *(const float4*)(Ap + k0 + 16);
            wv = *(const float4*)(Wp + (size_t)(k0 + 16) * N);
        }
#pragma unroll
        for (int kk = 0; kk < 16; ++kk) {
            float4 a4 = *(const float4*)(&As[kk][ty * 4]);
            float4 w4 = *(const float4*)(&Ws[kk][tx * 4]);
            acc[0][0] += a4.x * w4.x; acc[0][1] += a4.x * w4.y; acc[0][2] += a4.x * w4.z; acc[0][3] += a4.x * w4.w;
            acc[1][0] += a4.y * w4.x; acc[1][1] += a4.y * w4.y; acc[1][2] += a4.y * w4.z; acc[1][3] += a4.y * w4.w;
            acc[2][0] += a4.z * w4.x; acc[2][1] += a4.z * w4.y; acc[2][2] += a4.z * w4.z; acc[2][3] += a4.z * w4.w;
            acc[3][0] += a4.w * w4.x; acc[3][1] += a4.w * w4.y; acc[3][2] += a4.w * w4.z; acc[3][3] += a4.w * w4.w;
        }
        __syncthreads();
    }
#pragma unroll
    for (int i = 0; i < 4; ++i) {
        int cm = m0 + ty * 4 + i;
#pragma unroll
        for (int j = 0; j < 4; ++j) {
            int cn = n0 + tx * 4 + j;
            float v = acc[i][j] + bias[cn];
            if (act == 1) v = gelu_f(v);
            float* cp = Cp + (size_t)cm * N + cn;
            if (resid) v += *cp;
            *cp = v;
        }
    }
}

__global__ __launch_bounds__(256) void gemm_kernel(
    const float* __restrict__ A, const float* __restrict__ W,
    const float* __restrict__ bias, float* __restrict__ C,
    int M, int N, int K, int act, int resid)
{
    gemm_core(A, W, bias, C, N, K, act, resid, blockIdx.y * 64, blockIdx.x * 64);
}

// fused QK|V: grid (8,64); blocks x<4 compute W1->C1, else W2->C2. N=256 each.
__global__ __launch_bounds__(256) void gemm_qkv_kernel(
    const float* __restrict__ A,
    const float* __restrict__ W1, const float* __restrict__ b1, float* __restrict__ C1,
    const float* __restrict__ W2, const float* __restrict__ b2, float* __restrict__ C2,
    int K)
{
    int side = blockIdx.x >> 2;
    const float* W = side ? W2 : W1;
    const float* b = side ? b2 : b1;
    float* C = side ? C2 : C1;
    gemm_core(A, W, b, C, 256, K, 0, 0, blockIdx.y * 64, (blockIdx.x & 3) * 64);
}

__global__ __launch_bounds__(256) void knorm_kernel(
    const float* __restrict__ qk, float* __restrict__ knrm)
{
    int t = blockIdx.x * 256 + threadIdx.x;
    int h = t >> 12, n = t & 4095;
    const float* q = qk + (size_t)n * 256 + h * 64;
    float s = 0.f;
#pragma unroll
    for (int d = 0; d < 64; d += 4) {
        float4 v = *(const float4*)(q + d);
        s += v.x * v.x + v.y * v.y + v.z * v.z + v.w * v.w;
    }
    knrm[t] = 1.f / (sqrtf(s) + 1e-6f);
}

__global__ __launch_bounds__(256) void bucket_kernel(
    const float* __restrict__ qk, const float* __restrict__ rot,
    int* __restrict__ buckets)
{
    int t = blockIdx.x * 256 + threadIdx.x;
    int h = t >> 12, n = t & 4095;
    const float* q = qk + (size_t)n * 256 + h * 64;
    const float* R = rot + (size_t)h * 2048;
    float acc[32];
#pragma unroll
    for (int r = 0; r < 32; ++r) acc[r] = 0.f;
    for (int d = 0; d < 64; ++d) {
        float qd = q[d];
        const float* Rd = R + d * 32;
#pragma unroll
        for (int r = 0; r < 32; ++r) acc[r] += qd * Rd[r];
    }
    float bvv = acc[0]; int best = 0;
#pragma unroll
    for (int j = 1; j < 64; ++j) {
        float val = (j < 32) ? acc[j] : -acc[j - 32];
        if (val > bvv) { bvv = val; best = j; }
    }
    buckets[t] = best;
}

__global__ __launch_bounds__(256) void lsh_sort_kernel(
    const int* __restrict__ buckets, int* __restrict__ perm)
{
    int h = blockIdx.x;
    const int* bk = buckets + h * 4096;
    __shared__ unsigned long long mask[64][64];
    __shared__ int counts[64];
    __shared__ int offsets[64];
    __shared__ int wpre[64][64];
    int tid = threadIdx.x, wave = tid >> 6, lane = tid & 63;
    for (int w = wave * 16; w < wave * 16 + 16; ++w) {
        int bl = bk[w * 64 + lane];
        for (int b = 0; b < 64; ++b) {
            unsigned long long m = __ballot(bl == b);
            if (lane == b) mask[b][w] = m;
        }
    }
    __syncthreads();
    if (tid < 64) {
        int c = 0;
        for (int w = 0; w < 64; ++w) c += __popcll(mask[tid][w]);
        counts[tid] = c;
    }
    __syncthreads();
    if (tid == 0) {
        int a = 0;
        for (int b = 0; b < 64; ++b) { offsets[b] = a; a += counts[b]; }
    }
    __syncthreads();
    for (int b = wave * 16; b < wave * 16 + 16; ++b) {
        int c = __popcll(mask[b][lane]);
        int incl = c;
#pragma unroll
        for (int off = 1; off < 64; off <<= 1) {
            int nb = __shfl_up(incl, off);
            if (lane >= off) incl += nb;
        }
        wpre[b][lane] = incl - c + offsets[b];
    }
    __syncthreads();
    for (int i = tid; i < 4096; i += 256) {
        int b = bk[i]; int w = i >> 6; int l = i & 63;
        unsigned long long below = mask[b][w] & ((1ull << l) - 1ull);
        int pos = wpre[b][w] + __popcll(below);
        perm[h * 4096 + pos] = i;
    }
}

__global__ __launch_bounds__(256) void attn_kernel(
    const float* __restrict__ qk, const float* __restrict__ vv,
    const float* __restrict__ knrm, const int* __restrict__ perm,
    float* __restrict__ o, short* __restrict__ oh)
{
    __shared__ float ks[128 * 64];
    __shared__ float dotsT[128 * 64];
    int c = blockIdx.x, h = blockIdx.y;
    int tid = threadIdx.x;
    const int* pm = perm + h * 4096;
    int cm = (c + 63) & 63;
    {
        int jr = tid >> 1, hf = tid & 1;
        int sk = (jr < 64) ? (c * 64 + jr) : (cm * 64 + (jr - 64));
        int nk = pm[sk];
        float sc = knrm[h * 4096 + nk];
        const float* src = qk + (size_t)nk * 256 + h * 64 + hf * 32;
        float* dst = ks + jr * 64 + hf * 32;
#pragma unroll
        for (int d = 0; d < 32; d += 4) {
            float4 v = *(const float4*)(src + d);
            v.x *= sc; v.y *= sc; v.z *= sc; v.w *= sc;
            *(float4*)(dst + d) = v;
        }
    }
    __syncthreads();
    int r = tid & 63, jg = tid >> 6;
    int nq = pm[c * 64 + r];
    {
        float qreg[64];
        const float* src = qk + (size_t)nq * 256 + h * 64;
#pragma unroll
        for (int d = 0; d < 64; d += 4) {
            float4 v = *(const float4*)(src + d);
            qreg[d] = v.x; qreg[d + 1] = v.y; qreg[d + 2] = v.z; qreg[d + 3] = v.w;
        }
        for (int j = jg * 32; j < jg * 32 + 32; ++j) {
            const float* kr = ks + j * 64;
            float dot = 0.f;
#pragma unroll
            for (int d = 0; d < 64; ++d) dot += qreg[d] * kr[d];
            int sk = (j < 64) ? (c * 64 + j) : (cm * 64 + (j - 64));
            int nk = pm[sk];
            dot = (nk == nq) ? -1e5f : dot * 0.125f;
            dotsT[j * 64 + r] = dot;
        }
    }
    __syncthreads();
    {
        int jr = tid >> 1, hf = tid & 1;
        int sk = (jr < 64) ? (c * 64 + jr) : (cm * 64 + (jr - 64));
        int nk = pm[sk];
        const float* src = vv + (size_t)nk * 256 + h * 64 + hf * 32;
        float* dst = ks + jr * 64 + hf * 32;
#pragma unroll
        for (int d = 0; d < 32; d += 4)
            *(float4*)(dst + d) = *(const float4*)(src + d);
    }
    if (tid < 64) {
        int rr = tid;
        float mx = -1e30f;
        for (int j = 0; j < 128; ++j) mx = fmaxf(mx, dotsT[j * 64 + rr]);
        float s = 0.f;
        for (int j = 0; j < 128; ++j) {
            float e = expf(dotsT[j * 64 + rr] - mx);
            dotsT[j * 64 + rr] = e; s += e;
        }
        float inv = 1.f / s;
        for (int j = 0; j < 128; ++j) dotsT[j * 64 + rr] *= inv;
    }
    __syncthreads();
    int dg = jg;
    float acc[16];
#pragma unroll
    for (int d = 0; d < 16; ++d) acc[d] = 0.f;
    for (int j = 0; j < 128; ++j) {
        float a = dotsT[j * 64 + r];
        const float* vr = ks + j * 64 + dg * 16;
#pragma unroll
        for (int d = 0; d < 16; ++d) acc[d] += a * vr[d];
    }
    size_t ob = (size_t)nq * 256 + h * 64 + dg * 16;
    float* dst = o + ob;
    short* dsth = oh + ob;
#pragma unroll
    for (int d = 0; d < 16; d += 4) {
        float4 v = { acc[d], acc[d + 1], acc[d + 2], acc[d + 3] };
        *(float4*)(dst + d) = v;
        dsth[d] = f2h(v.x); dsth[d+1] = f2h(v.y);
        dsth[d+2] = f2h(v.z); dsth[d+3] = f2h(v.w);
    }
}

// ============================================================================
// FP16 MFMA kernels (post-bucket tail + decoder)
// ============================================================================

__global__ void pack_gemm_kernel(const float* __restrict__ W, short* __restrict__ Bp,
                                 int N, int total)
{
    int t = blockIdx.x * 256 + threadIdx.x;
    if (t >= total) return;
    int lane = t & 63, fi = t >> 6;
    int NT = N >> 4;
    int nt = fi % NT, kt = fi / NT;
    int n = nt * 16 + (lane & 15);
    int k0 = kt * 32 + (lane >> 4) * 8;
    short8 v;
#pragma unroll
    for (int j = 0; j < 8; ++j) v[j] = f2h(W[(size_t)(k0 + j) * N + n]);
    ((short8*)Bp)[t] = v;
}

__global__ void pack_conv_kernel(const float* __restrict__ w, short* __restrict__ Bp,
                                 int C, int OC, int NT, int total)
{
    int t = blockIdx.x * 256 + threadIdx.x;
    if (t >= total) return;
    int lane = t & 63, fi = t >> 6;
    int nt = fi % NT, kt = fi / NT;
    int cpt = C >> 5;
    int tap = kt / cpt, ct = kt % cpt;
    int c = ct * 32 + (lane >> 4) * 8;
    int oc = nt * 16 + (lane & 15);
    short8 v;
#pragma unroll
    for (int j = 0; j < 8; ++j) {
        float f = (oc < OC) ? w[((size_t)oc * C + c + j) * 9 + tap] : 0.f;
        v[j] = f2h(f);
    }
    ((short8*)Bp)[t] = v;
}

__global__ void pack_convt_kernel(const float* __restrict__ w, short* __restrict__ Bp,
                                  int IC, int OC, int total)
{
    int t = blockIdx.x * 256 + threadIdx.x;
    if (t >= total) return;
    int lane = t & 63, fi = t >> 6;
    int NT = OC >> 4, cpt = IC >> 5, KT4 = 4 * cpt;
    int nt = fi % NT, r = fi / NT;
    int kt = r % KT4, pz = r / KT4;
    int py = pz >> 1, px = pz & 1;
    int t4 = kt / cpt, ct = kt % cpt;
    int ty = t4 >> 1, tx = t4 & 1;
    int ky = py ? (2 * ty) : (1 + 2 * ty);
    int kx = px ? (2 * tx) : (1 + 2 * tx);
    int ic = ct * 32 + (lane >> 4) * 8;
    int oc = nt * 16 + (lane & 15);
    short8 v;
#pragma unroll
    for (int j = 0; j < 8; ++j)
        v[j] = f2h(w[(((size_t)(ic + j) * OC + oc) * 4 + ky) * 4 + kx]);
    ((short8*)Bp)[t] = v;
}

__global__ __launch_bounds__(256) void gemm_mfma_kernel(
    const short* __restrict__ A, const short* __restrict__ Bp,
    const float* __restrict__ bias, float* __restrict__ Cf, short* __restrict__ Cb,
    int M, int N, int K, int act, int resid)
{
    int tid = threadIdx.x, wave = tid >> 6, lane = tid & 63;
    int quad = lane >> 4, l16 = lane & 15;
    int m0 = blockIdx.y * 64 + wave * 16;
    int NT = N >> 4;
    int nt0 = blockIdx.x * 4;
    const half8* arow = (const half8*)(A + (size_t)(m0 + l16) * K + quad * 8);
    const half8* bp = (const half8*)Bp;
    floatx4 acc0 = {0,0,0,0}, acc1 = {0,0,0,0}, acc2 = {0,0,0,0}, acc3 = {0,0,0,0};
    int KT = K >> 5;
    for (int kt = 0; kt < KT; ++kt) {
        half8 a = arow[kt * 4];
        size_t bi = ((size_t)kt * NT + nt0) * 64 + lane;
        acc0 = __builtin_amdgcn_mfma_f32_16x16x32_f16(a, bp[bi      ], acc0, 0, 0, 0);
        acc1 = __builtin_amdgcn_mfma_f32_16x16x32_f16(a, bp[bi +  64], acc1, 0, 0, 0);
        acc2 = __builtin_amdgcn_mfma_f32_16x16x32_f16(a, bp[bi + 128], acc2, 0, 0, 0);
        acc3 = __builtin_amdgcn_mfma_f32_16x16x32_f16(a, bp[bi + 192], acc3, 0, 0, 0);
    }
    floatx4 accs[4] = {acc0, acc1, acc2, acc3};
#pragma unroll
    for (int s = 0; s < 4; ++s) {
        int n = (nt0 + s) * 16 + l16;
        float bs = bias[n];
#pragma unroll
        for (int r = 0; r < 4; ++r) {
            int m = m0 + quad * 4 + r;
            float v = accs[s][r] + bs;
            if (act == 1) v = gelu_f(v);
            size_t o = (size_t)m * N + n;
            if (resid) v += Cf[o];
            if (Cb) Cb[o] = f2h(v);
            else    Cf[o] = v;
        }
    }
}

__global__ __launch_bounds__(256) void conv_mfma_kernel(
    const short* __restrict__ in1, int C1, const short* __restrict__ in2, int C2,
    const short* __restrict__ Bp, const float* __restrict__ bias,
    float* __restrict__ outf, short* __restrict__ outb, int H, int W, int OC)
{
    int tid = threadIdx.x, wave = tid >> 6, lane = tid & 63;
    int quad = lane >> 4, l16 = lane & 15;
    int x0 = blockIdx.x * 64, y = blockIdx.y, nt0 = blockIdx.z * 4;
    int C = C1 + C2, cpt = C >> 5, NT = OC >> 4;
    const half8* bp = (const half8*)Bp;
    floatx4 acc0 = {0,0,0,0}, acc1 = {0,0,0,0}, acc2 = {0,0,0,0}, acc3 = {0,0,0,0};
    int xm = x0 + wave * 16 + l16;
    for (int ky = 0; ky < 3; ++ky) {
        int yy = y + ky - 1;
        bool rok = (yy >= 0) && (yy < H);
        for (int kx = 0; kx < 3; ++kx) {
            int xx = xm + kx - 1;
            bool ok = rok && (xx >= 0) && (xx < W);
            int pos = yy * W + xx;
            int ktb = (ky * 3 + kx) * cpt;
            for (int ct = 0; ct < cpt; ++ct) {
                int cc = ct * 32 + quad * 8;
                half8 a = {};
                if (ok) {
                    const short* src = (cc < C1) ? (in1 + (size_t)pos * C1 + cc)
                                                 : (in2 + (size_t)pos * C2 + (cc - C1));
                    a = *(const half8*)src;
                }
                size_t bi = ((size_t)(ktb + ct) * NT + nt0) * 64 + lane;
                acc0 = __builtin_amdgcn_mfma_f32_16x16x32_f16(a, bp[bi      ], acc0, 0, 0, 0);
                acc1 = __builtin_amdgcn_mfma_f32_16x16x32_f16(a, bp[bi +  64], acc1, 0, 0, 0);
                acc2 = __builtin_amdgcn_mfma_f32_16x16x32_f16(a, bp[bi + 128], acc2, 0, 0, 0);
                acc3 = __builtin_amdgcn_mfma_f32_16x16x32_f16(a, bp[bi + 192], acc3, 0, 0, 0);
            }
        }
    }
    floatx4 accs[4] = {acc0, acc1, acc2, acc3};
#pragma unroll
    for (int s = 0; s < 4; ++s) {
        int n = (nt0 + s) * 16 + l16;
        float bs = bias[n];
#pragma unroll
        for (int r = 0; r < 4; ++r) {
            int m = wave * 16 + quad * 4 + r;
            int x = x0 + m;
            float v = fmaxf(accs[s][r] + bs, 0.f);
            size_t o = ((size_t)y * W + x) * OC + n;
            if (outb) outb[o] = f2h(v);
            else      outf[o] = v;
        }
    }
}

__global__ __launch_bounds__(256) void convt_mfma_kernel(
    const short* __restrict__ in, int IC, const short* __restrict__ Bp,
    const float* __restrict__ bias, short* __restrict__ outb, int IH, int IW, int OC)
{
    int tid = threadIdx.x, wave = tid >> 6, lane = tid & 63;
    int quad = lane >> 4, l16 = lane & 15;
    int pz = blockIdx.z & 3, nt0 = (blockIdx.z >> 2) * 4;
    int py = pz >> 1, px = pz & 1;
    int a0 = blockIdx.y, b0 = blockIdx.x * 64;
    int cpt = IC >> 5, NT = OC >> 4, KT4 = 4 * cpt;
    const half8* bp = (const half8*)Bp;
    floatx4 acc0 = {0,0,0,0}, acc1 = {0,0,0,0}, acc2 = {0,0,0,0}, acc3 = {0,0,0,0};
    int bm = b0 + wave * 16 + l16;
    for (int ty = 0; ty < 2; ++ty) {
        int iy = a0 + (py ? (1 - ty) : (-ty));
        bool rok = (iy >= 0) && (iy < IH);
        for (int tx = 0; tx < 2; ++tx) {
            int ix = bm + (px ? (1 - tx) : (-tx));
            bool ok = rok && (ix >= 0) && (ix < IW);
            int pos = iy * IW + ix;
            int ktb = (ty * 2 + tx) * cpt;
            for (int ct = 0; ct < cpt; ++ct) {
                int cc = ct * 32 + quad * 8;
                half8 a = {};
                if (ok) a = *(const half8*)(in + (size_t)pos * IC + cc);
                size_t bi = ((size_t)(pz * KT4 + ktb + ct) * NT + nt0) * 64 + lane;
                acc0 = __builtin_amdgcn_mfma_f32_16x16x32_f16(a, bp[bi      ], acc0, 0, 0, 0);
                acc1 = __builtin_amdgcn_mfma_f32_16x16x32_f16(a, bp[bi +  64], acc1, 0, 0, 0);
                acc2 = __builtin_amdgcn_mfma_f32_16x16x32_f16(a, bp[bi + 128], acc2, 0, 0, 0);
                acc3 = __builtin_amdgcn_mfma_f32_16x16x32_f16(a, bp[bi + 192], acc3, 0, 0, 0);
            }
        }
    }
    floatx4 accs[4] = {acc0, acc1, acc2, acc3};
    int OW = IW * 2;
    int oy = 2 * a0 + py;
#pragma unroll
    for (int s = 0; s < 4; ++s) {
        int n = (nt0 + s) * 16 + l16;
        float bs = bias[n];
#pragma unroll
        for (int r = 0; r < 4; ++r) {
            int m = wave * 16 + quad * 4 + r;
            int ox = 2 * (b0 + m) + px;
            float v = accs[s][r] + bs;
            outb[((size_t)oy * OW + ox) * OC + n] = f2h(v);
        }
    }
}

__global__ __launch_bounds__(256) void convout_mfma_kernel(
    const short* __restrict__ in, const short* __restrict__ Bp,
    const float* __restrict__ bias, float* __restrict__ out, int H, int W)
{
    int tid = threadIdx.x, wave = tid >> 6, lane = tid & 63;
    int quad = lane >> 4, l16 = lane & 15;
    int x0 = blockIdx.x * 64, y = blockIdx.y;
    const int C = 64, cpt = 2;
    const half8* bp = (const half8*)Bp;
    floatx4 acc = {0,0,0,0};
    int xm = x0 + wave * 16 + l16;
    for (int ky = 0; ky < 3; ++ky) {
        int yy = y + ky - 1;
        bool rok = (yy >= 0) && (yy < H);
        for (int kx = 0; kx < 3; ++kx) {
            int xx = xm + kx - 1;
            bool ok = rok && (xx >= 0) && (xx < W);
            int pos = yy * W + xx;
            int ktb = (ky * 3 + kx) * cpt;
#pragma unroll
            for (int ct = 0; ct < cpt; ++ct) {
                int cc = ct * 32 + quad * 8;
                half8 a = {};
                if (ok) a = *(const half8*)(in + (size_t)pos * C + cc);
                acc = __builtin_amdgcn_mfma_f32_16x16x32_f16(
                          a, bp[(size_t)(ktb + ct) * 64 + lane], acc, 0, 0, 0);
            }
        }
    }
    int oc = l16;
    if (oc < 3) {
        float bs = bias[oc];
#pragma unroll
        for (int r = 0; r < 4; ++r) {
            int m = wave * 16 + quad * 4 + r;
            int x = x0 + m;
            float v = acc[r] + bs;
            v = 1.f / (1.f + expf(-v));
            out[(size_t)oc * H * W + (size_t)y * W + x] = v;
        }
    }
}

__global__ __launch_bounds__(256) void nchw2nhwc_h_kernel(
    const float* __restrict__ in, short* __restrict__ out, int C, int HW)
{
    __shared__ float t[32][33];
    int c0 = blockIdx.y * 32, p0 = blockIdx.x * 32;
    int tid = threadIdx.x;
#pragma unroll
    for (int it = 0; it < 4; ++it) {
        int i = tid + it * 256;
        int lc = i >> 5, lp = i & 31;
        t[lc][lp] = in[(size_t)(c0 + lc) * HW + p0 + lp];
    }
    __syncthreads();
#pragma unroll
    for (int it = 0; it < 4; ++it) {
        int i = tid + it * 256;
        int lp = i >> 5, lc = i & 31;
        out[(size_t)(p0 + lp) * C + c0 + lc] = f2h(t[lc][lp]);
    }
}

__global__ __launch_bounds__(256) void f2h_kernel(
    const float* __restrict__ in, short* __restrict__ out, int n)
{
    int i = blockIdx.x * 256 + threadIdx.x;
    if (i < n) out[i] = f2h(in[i]);
}

// ============================================================================
extern "C" void kernel_launch(void* const* d_in, const int* in_sizes, int n_in,
                              void* d_out, int out_size, void* d_ws, size_t ws_size,
                              hipStream_t stream)
{
    const float* burst   = (const float*)d_in[0];
    const float* conv1_w = (const float*)d_in[1];  const float* conv1_b = (const float*)d_in[2];
    const float* conv2_w = (const float*)d_in[3];  const float* conv2_b = (const float*)d_in[4];
    const float* conv3_w = (const float*)d_in[5];  const float* conv3_b = (const float*)d_in[6];
    const float* ln1_g   = (const float*)d_in[7];  const float* ln1_b   = (const float*)d_in[8];
    const float* Wqk     = (const float*)d_in[9];  const float* bqk     = (const float*)d_in[10];
    const float* Wv      = (const float*)d_in[11]; const float* bvv     = (const float*)d_in[12];
    const float* Wo      = (const float*)d_in[13]; const float* bo      = (const float*)d_in[14];
    const float* rot     = (const float*)d_in[15];
    const float* ln2_g   = (const float*)d_in[16]; const float* ln2_b   = (const float*)d_in[17];
    const float* Wff1    = (const float*)d_in[18]; const float* bff1    = (const float*)d_in[19];
    const float* Wff2    = (const float*)d_in[20]; const float* bff2    = (const float*)d_in[21];
    const float* up1_w   = (const float*)d_in[22]; const float* up1_b   = (const float*)d_in[23];
    const float* dec1_w  = (const float*)d_in[24]; const float* dec1_b  = (const float*)d_in[25];
    const float* up2_w   = (const float*)d_in[26]; const float* up2_b   = (const float*)d_in[27];
    const float* dec2_w  = (const float*)d_in[28]; const float* dec2_b  = (const float*)d_in[29];
    const float* out_w   = (const float*)d_in[30]; const float* out_b   = (const float*)d_in[31];

    float* ws = (float*)d_ws;
    float* e1   = ws + 0;          // 64*256*256
    float* e2   = ws + 4194304;    // 128*128*128
    float* p1   = ws + 6291456;    // 64*128*128   (dead after conv2)
    float* p2   = ws + 7340032;    // 128*64*64    (dead after conv3)
    float* seq  = ws + 7864320;    // 4096*256
    float* xn   = ws + 8912896;
    float* qkb  = ws + 9961472;
    float* vvb  = ws + 11010048;
    float* oob  = ws + 12058624;
    float* hdn  = ws + 13107200;   // 4096*1024 (layers 0-2)
    float* knb  = ws + 17301504;
    int* buckets = (int*)(ws + 17317888);
    int* perm    = (int*)(ws + 17334272);
    short* xnh  = (short*)p1;
    short* seqh = (short*)(ws + 6815744);
    short* ooh  = (short*)p2;
    short* hdnh = (short*)hdn;
    short* e1h  = (short*)(ws + 15204352);
    short* e2h  = (short*)vvb;
    short* d1   = (short*)xn;
    short* d1c  = (short*)qkb;
    short* d2   = (short*)hdn;
    short* d2c  = (short*)e2;
    short* pk    = (short*)(ws + 17350656);
    short* ppo   = pk + 65536;     // 65536
    short* ppf1  = pk + 131072;    // 262144
    short* ppf2  = pk + 393216;    // 262144
    short* pdec1 = pk + 655360;    // 294912
    short* pdec2 = pk + 950272;    // 73728
    short* pout  = pk + 1024000;   // 9216
    short* pup1  = pk + 1033216;   // 524288
    short* pup2  = pk + 1557504;   // 131072

    dim3 b16(16, 16);

    // ---- weight packing (layer-3 tail + decoder)
    pack_gemm_kernel<<<32, 256, 0, stream>>>(Wo  + 3 * 65536,  ppo,  256, 8192);
    pack_gemm_kernel<<<128, 256, 0, stream>>>(Wff1 + 3 * 262144, ppf1, 1024, 32768);
    pack_gemm_kernel<<<128, 256, 0, stream>>>(Wff2 + 3 * 262144, ppf2, 256, 32768);
    pack_conv_kernel<<<144, 256, 0, stream>>>(dec1_w, pdec1, 256, 128, 8, 36864);
    pack_conv_kernel<<<36, 256, 0, stream>>>(dec2_w, pdec2, 128, 64, 4, 9216);
    pack_conv_kernel<<<5, 256, 0, stream>>>(out_w,  pout,  64, 3, 1, 1152);
    pack_convt_kernel<<<256, 256, 0, stream>>>(up1_w, pup1, 256, 128, 65536);
    pack_convt_kernel<<<64, 256, 0, stream>>>(up2_w, pup2, 128, 64, 16384);

    // ---- encoder (fp32, bucket-critical)
    conv3x3_kernel<8><<<dim3(16, 16, 8), b16, 0, stream>>>(
        burst, 3, nullptr, 0, conv1_w, conv1_b, e1, 256, 256, 64, 1, 0);
    maxpool_kernel<<<4096, 256, 0, stream>>>(e1, p1, 64, 256, 256);
    conv3x3_lds_kernel<<<dim3(8, 8, 16), 256, 0, stream>>>(
        p1, conv2_w, conv2_b, e2, 128, 128, 64, 128, 0);
    maxpool_kernel<<<2048, 256, 0, stream>>>(e2, p2, 128, 128, 128);
    conv3x3_lds_kernel<<<dim3(4, 4, 32), 256, 0, stream>>>(
        p2, conv3_w, conv3_b, seq, 64, 64, 128, 256, 1);

    // ---- reformer layers 0-2 (fp32, bucket-critical)
    for (int i = 0; i < 3; ++i) {
        ln_kernel<<<1024, 256, 0, stream>>>(seq, ln1_g + i * 256, ln1_b + i * 256, xn, xnh);
        gemm_qkv_kernel<<<dim3(8, 64), 256, 0, stream>>>(
            xn, Wqk + i * 65536, bqk + i * 256, qkb,
            Wv + i * 65536, bvv + i * 256, vvb, 256);
        knorm_kernel<<<64, 256, 0, stream>>>(qkb, knb);
        bucket_kernel<<<64, 256, 0, stream>>>(qkb, rot + i * 8192, buckets);
        lsh_sort_kernel<<<4, 256, 0, stream>>>(buckets, perm);
        attn_kernel<<<dim3(64, 4), 256, 0, stream>>>(qkb, vvb, knb, perm, oob, ooh);
        gemm_kernel<<<dim3(4, 64), 256, 0, stream>>>(oob, Wo + i * 65536, bo + i * 256,
                                                     seq, 4096, 256, 256, 0, 1);
        ln_kernel<<<1024, 256, 0, stream>>>(seq, ln2_g + i * 256, ln2_b + i * 256, xn, xnh);
        gemm_kernel<<<dim3(16, 64), 256, 0, stream>>>(xn, Wff1 + i * 262144, bff1 + i * 1024,
                                                      hdn, 4096, 1024, 256, 1, 0);
        gemm_kernel<<<dim3(4, 64), 256, 0, stream>>>(hdn, Wff2 + i * 262144, bff2 + i * 256,
                                                     seq, 4096, 256, 1024, 0, 1);
    }

    // ---- layer 3: fp32 QK/V (bucket path exact) + fp16 MFMA tail
    {
        const int i = 3;
        ln_kernel<<<1024, 256, 0, stream>>>(seq, ln1_g + i * 256, ln1_b + i * 256, xn, xnh);
        gemm_qkv_kernel<<<dim3(8, 64), 256, 0, stream>>>(
            xn, Wqk + i * 65536, bqk + i * 256, qkb,
            Wv + i * 65536, bvv + i * 256, vvb, 256);
        knorm_kernel<<<64, 256, 0, stream>>>(qkb, knb);
        bucket_kernel<<<64, 256, 0, stream>>>(qkb, rot + i * 8192, buckets);
        lsh_sort_kernel<<<4, 256, 0, stream>>>(buckets, perm);
        attn_kernel<<<dim3(64, 4), 256, 0, stream>>>(qkb, vvb, knb, perm, oob, ooh);
        gemm_mfma_kernel<<<dim3(4, 64), 256, 0, stream>>>(
            ooh, ppo, bo + i * 256, seq, nullptr, 4096, 256, 256, 0, 1);
        ln_kernel<<<1024, 256, 0, stream>>>(seq, ln2_g + i * 256, ln2_b + i * 256, xn, xnh);
        gemm_mfma_kernel<<<dim3(16, 64), 256, 0, stream>>>(
            xnh, ppf1, bff1 + i * 1024, nullptr, hdnh, 4096, 1024, 256, 1, 0);
        gemm_mfma_kernel<<<dim3(4, 64), 256, 0, stream>>>(
            hdnh, ppf2, bff2 + i * 256, seq, nullptr, 4096, 256, 1024, 0, 1);
    }

    // ---- layout conversions for the MFMA decoder
    nchw2nhwc_h_kernel<<<dim3(2048, 2), 256, 0, stream>>>(e1, e1h, 64, 65536);
    nchw2nhwc_h_kernel<<<dim3(512, 4), 256, 0, stream>>>(e2, e2h, 128, 16384);
    f2h_kernel<<<4096, 256, 0, stream>>>(seq, seqh, 1048576);

    // ---- decoder (fp16 MFMA)
    convt_mfma_kernel<<<dim3(1, 64, 8), 256, 0, stream>>>(
        seqh, 256, pup1, up1_b, d1, 64, 64, 128);
    conv_mfma_kernel<<<dim3(2, 128, 2), 256, 0, stream>>>(
        d1, 128, e2h, 128, pdec1, dec1_b, nullptr, d1c, 128, 128, 128);
    convt_mfma_kernel<<<dim3(2, 128, 4), 256, 0, stream>>>(
        d1c, 128, pup2, up2_b, d2, 128, 128, 64);
    conv_mfma_kernel<<<dim3(4, 256, 1), 256, 0, stream>>>(
        d2, 64, e1h, 64, pdec2, dec2_b, nullptr, d2c, 256, 256, 64);
    convout_mfma_kernel<<<dim3(4, 256), 256, 0, stream>>>(
        d2c, pout, out_b, (float*)d_out, 256, 256);
}